// Round 1
// baseline (7562.438 us; speedup 1.0000x reference)
//
#include <hip/hip_runtime.h>
#include <hip/hip_bf16.h>
#include <cstdint>

// ---------------------------------------------------------------------------
// 3-layer GCN on MI355X.
// Pipeline per call (all on `stream`, graph-capture safe):
//   1. cnt[i]   = in-degree (atomics over E)
//   2. dinv[i]  = rsqrt(cnt+1)  (self-loop included), cursor=0
//   3. rs[]     = exclusive scan of cnt (3-kernel scan), rs[N]=E
//   4. CSR fill: edges grouped by dst, weight w = dinv[src]*dinv[dst]
//   5. R = x@Wr + br        (residual GEMM)
//   6. A = x@W0;  OUT  = relu(S(A)+b0) + R      (S = normalized adjacency)
//   7. A = OUT@W1; R   = relu(S(A)+b1)
//   8. A = R@W2;  OUT  = relu(S(A)+b2)
// Aggregation is gather-style: one wave per node, no float atomics.
// ---------------------------------------------------------------------------

#define WS_ALIGN(x) (((x) + 255) & ~(size_t)255)

__global__ void k_zero_int(int* p, int n) {
  int i = blockIdx.x * blockDim.x + threadIdx.x;
  if (i < n) p[i] = 0;
}

__global__ void k_count(const int* __restrict__ dst, int E, int* __restrict__ cnt) {
  int e = blockIdx.x * blockDim.x + threadIdx.x;
  if (e < E) atomicAdd(&cnt[dst[e]], 1);
}

__global__ void k_dinv(const int* __restrict__ cnt, float* __restrict__ dinv,
                       int* __restrict__ cursor, int n) {
  int i = blockIdx.x * blockDim.x + threadIdx.x;
  if (i < n) {
    dinv[i] = rsqrtf((float)(cnt[i] + 1));  // +1 = self-loop; always > 0
    cursor[i] = 0;
  }
}

// Block-wise exclusive scan (Hillis-Steele in LDS), 1024 elems/block
__global__ __launch_bounds__(1024) void k_scan1(const int* __restrict__ cnt, int n,
                                                int* __restrict__ rs, int* __restrict__ bsum) {
  __shared__ int tmp[1024];
  int tid = threadIdx.x;
  int i = blockIdx.x * 1024 + tid;
  int v = (i < n) ? cnt[i] : 0;
  tmp[tid] = v;
  __syncthreads();
  for (int off = 1; off < 1024; off <<= 1) {
    int t = (tid >= off) ? tmp[tid - off] : 0;
    __syncthreads();
    tmp[tid] += t;
    __syncthreads();
  }
  if (i < n) rs[i] = tmp[tid] - v;           // exclusive
  if (tid == 1023) bsum[blockIdx.x] = tmp[1023];
}

// Single-block scan of the (<=128) block sums
__global__ __launch_bounds__(128) void k_scan2(int* bsum, int nb) {
  __shared__ int tmp[128];
  int tid = threadIdx.x;
  int v = (tid < nb) ? bsum[tid] : 0;
  tmp[tid] = v;
  __syncthreads();
  for (int off = 1; off < 128; off <<= 1) {
    int t = (tid >= off) ? tmp[tid - off] : 0;
    __syncthreads();
    tmp[tid] += t;
    __syncthreads();
  }
  if (tid < nb) bsum[tid] = tmp[tid] - v;    // exclusive
}

__global__ void k_scan3(int* rs, const int* __restrict__ bsum, int n, int E) {
  int i = blockIdx.x * blockDim.x + threadIdx.x;
  if (i < n) rs[i] += bsum[i >> 10];
  if (i == 0) rs[n] = E;
}

__global__ void k_fill(const int* __restrict__ src, const int* __restrict__ dst, int E,
                       const int* __restrict__ rs, int* __restrict__ cursor,
                       const float* __restrict__ dinv,
                       int* __restrict__ csrc, float* __restrict__ cw) {
  int e = blockIdx.x * blockDim.x + threadIdx.x;
  if (e < E) {
    int s = src[e], d = dst[e];
    int pos = atomicAdd(&cursor[d], 1);
    int idx = rs[d] + pos;
    csrc[idx] = s;
    cw[idx] = dinv[s] * dinv[d];
  }
}

// C[N,128] = X[N,128] @ W[128,128] (+bias). W staged in LDS (64 KB).
// Block: 256 threads -> 64 rows; thread = 8 rows x 4 cols register tile.
__global__ __launch_bounds__(256) void k_gemm128(const float* __restrict__ X,
                                                 const float* __restrict__ W,
                                                 const float* __restrict__ bias,
                                                 float* __restrict__ Y, int n) {
  __shared__ float4 sW4[128 * 32];
  const float4* W4 = (const float4*)W;
  for (int i = threadIdx.x; i < 128 * 32; i += 256) sW4[i] = W4[i];
  __syncthreads();

  int tx = threadIdx.x & 31;   // col group: cols [4*tx, 4*tx+3]
  int ty = threadIdx.x >> 5;   // 0..7
  int r0 = blockIdx.x * 64 + ty * 8;
  int rc[8];
#pragma unroll
  for (int rr = 0; rr < 8; rr++) { int r = r0 + rr; rc[rr] = (r < n) ? r : (n - 1); }

  const float4* X4 = (const float4*)X;
  float acc[8][4] = {};
  for (int k4 = 0; k4 < 32; k4++) {
    float4 xv[8];
#pragma unroll
    for (int rr = 0; rr < 8; rr++) xv[rr] = X4[(size_t)rc[rr] * 32 + k4];
#pragma unroll
    for (int kk = 0; kk < 4; kk++) {
      float4 w = sW4[(k4 * 4 + kk) * 32 + tx];
#pragma unroll
      for (int rr = 0; rr < 8; rr++) {
        float xs = (kk == 0) ? xv[rr].x : (kk == 1) ? xv[rr].y : (kk == 2) ? xv[rr].z : xv[rr].w;
        acc[rr][0] = fmaf(xs, w.x, acc[rr][0]);
        acc[rr][1] = fmaf(xs, w.y, acc[rr][1]);
        acc[rr][2] = fmaf(xs, w.z, acc[rr][2]);
        acc[rr][3] = fmaf(xs, w.w, acc[rr][3]);
      }
    }
  }

  float4 b4 = make_float4(0.f, 0.f, 0.f, 0.f);
  if (bias) b4 = ((const float4*)bias)[tx];
#pragma unroll
  for (int rr = 0; rr < 8; rr++) {
    int r = r0 + rr;
    if (r < n) {
      float4 o;
      o.x = acc[rr][0] + b4.x; o.y = acc[rr][1] + b4.y;
      o.z = acc[rr][2] + b4.z; o.w = acc[rr][3] + b4.w;
      ((float4*)Y)[(size_t)r * 32 + tx] = o;
    }
  }
}

// Gather aggregation: one wave (64 lanes) per node, lane -> 2 columns (float2).
// out = relu( sum_{e: dst=node} w_e * H[src_e] + dinv^2 * H[node] + bias ) [+ resid]
__global__ __launch_bounds__(256) void k_agg(const float* __restrict__ H,
                                             const int* __restrict__ rs,
                                             const int* __restrict__ csrc,
                                             const float* __restrict__ cw,
                                             const float* __restrict__ dinv,
                                             const float* __restrict__ bias,
                                             const float* __restrict__ resid,
                                             float* __restrict__ out, int n) {
  int gid = blockIdx.x * 256 + threadIdx.x;
  int node = gid >> 6;
  int lane = threadIdx.x & 63;
  if (node >= n) return;

  const float2* H2 = (const float2*)H;
  float di = dinv[node];
  float ws = di * di;
  float2 hv = H2[(size_t)node * 64 + lane];
  float ax = hv.x * ws, ay = hv.y * ws;

  int beg = rs[node], end = rs[node + 1];
  for (int j = beg; j < end; j++) {
    int s = csrc[j];           // wave-uniform
    float w = cw[j];           // wave-uniform
    float2 h2 = H2[(size_t)s * 64 + lane];   // 512B coalesced gather
    ax = fmaf(w, h2.x, ax);
    ay = fmaf(w, h2.y, ay);
  }

  float2 b2 = ((const float2*)bias)[lane];
  ax += b2.x; ay += b2.y;
  ax = fmaxf(ax, 0.f); ay = fmaxf(ay, 0.f);
  if (resid) {
    float2 r2 = ((const float2*)resid)[(size_t)node * 64 + lane];
    ax += r2.x; ay += r2.y;
  }
  float2 o; o.x = ax; o.y = ay;
  ((float2*)out)[(size_t)node * 64 + lane] = o;
}

extern "C" void kernel_launch(void* const* d_in, const int* in_sizes, int n_in,
                              void* d_out, int out_size, void* d_ws, size_t ws_size,
                              hipStream_t stream) {
  const float* x  = (const float*)d_in[0];
  const int* edges = (const int*)d_in[1];
  const float* W0 = (const float*)d_in[2];
  const float* b0 = (const float*)d_in[3];
  const float* W1 = (const float*)d_in[4];
  const float* b1 = (const float*)d_in[5];
  const float* W2 = (const float*)d_in[6];
  const float* b2 = (const float*)d_in[7];
  const float* Wr = (const float*)d_in[8];
  const float* br = (const float*)d_in[9];

  int N = in_sizes[0] / 128;
  int E = in_sizes[1] / 2;
  const int* src = edges;
  const int* dst = edges + E;

  char* ws = (char*)d_ws;
  size_t off = 0;
  auto alloc = [&](size_t bytes) -> void* {
    void* p = ws + off; off = WS_ALIGN(off + bytes); return p;
  };
  int*   cnt    = (int*)  alloc((size_t)N * 4);
  int*   cursor = (int*)  alloc((size_t)N * 4);
  float* dinv   = (float*)alloc((size_t)N * 4);
  int*   rs     = (int*)  alloc((size_t)(N + 1) * 4);
  int*   bsum   = (int*)  alloc(1024);
  int*   csrc   = (int*)  alloc((size_t)E * 4);
  float* cw     = (float*)alloc((size_t)E * 4);
  float* A      = (float*)alloc((size_t)N * 128 * 4);
  float* R      = (float*)alloc((size_t)N * 128 * 4);
  (void)ws_size; (void)n_in; (void)out_size;

  int nb1 = (N + 1023) / 1024;   // 98 for N=100000 (must be <= 128)

  // ---- normalization + CSR build ----
  k_zero_int<<<(N + 255) / 256, 256, 0, stream>>>(cnt, N);
  k_count  <<<(E + 255) / 256, 256, 0, stream>>>(dst, E, cnt);
  k_dinv   <<<(N + 255) / 256, 256, 0, stream>>>(cnt, dinv, cursor, N);
  k_scan1  <<<nb1, 1024, 0, stream>>>(cnt, N, rs, bsum);
  k_scan2  <<<1, 128, 0, stream>>>(bsum, nb1);
  k_scan3  <<<(N + 255) / 256, 256, 0, stream>>>(rs, bsum, N, E);
  k_fill   <<<(E + 255) / 256, 256, 0, stream>>>(src, dst, E, rs, cursor, dinv, csrc, cw);

  // ---- GCN layers ----
  float* OUT = (float*)d_out;
  int gb = (N + 63) / 64;
  int ab = (N * 64 + 255) / 256;  // one wave per node

  k_gemm128<<<gb, 256, 0, stream>>>(x, Wr, br, R, N);              // residual
  k_gemm128<<<gb, 256, 0, stream>>>(x, W0, nullptr, A, N);
  k_agg    <<<ab, 256, 0, stream>>>(A, rs, csrc, cw, dinv, b0, R, OUT, N);   // layer 0
  k_gemm128<<<gb, 256, 0, stream>>>(OUT, W1, nullptr, A, N);
  k_agg    <<<ab, 256, 0, stream>>>(A, rs, csrc, cw, dinv, b1, nullptr, R, N); // layer 1
  k_gemm128<<<gb, 256, 0, stream>>>(R, W2, nullptr, A, N);
  k_agg    <<<ab, 256, 0, stream>>>(A, rs, csrc, cw, dinv, b2, nullptr, OUT, N); // layer 2
}

// Round 2
// 1058.187 us; speedup vs baseline: 7.1466x; 7.1466x over previous
//
#include <hip/hip_runtime.h>
#include <hip/hip_bf16.h>
#include <cstdint>

// ---------------------------------------------------------------------------
// 3-layer GCN on MI355X.
// Pipeline per call (all on `stream`, graph-capture safe):
//   1. cnt[i]   = in-degree (atomics over E)
//   2. dinv[i]  = rsqrt(cnt+1)  (self-loop included), cursor=0
//   3. rs[]     = exclusive scan of cnt (3-kernel scan), rs[N]=E
//   4. CSR fill: edges grouped by dst, weight w = dinv[src]*dinv[dst]
//   5. R = x@Wr + br        (residual GEMM)
//   6. A = x@W0;  OUT  = relu(S(A)+b0) + R      (S = normalized adjacency)
//   7. A = OUT@W1; R   = relu(S(A)+b1)
//   8. A = R@W2;  OUT  = relu(S(A)+b2)
// Aggregation is gather-style: one wave per node, no float atomics.
//
// R1 fix: GEMM thread tile 8x4 -> 4x4, block 256->512, `#pragma unroll 2` on
// the k-loop. R1's compiler fully unrolled k (32x) and hoisted ~256 float4
// loads -> 256 VGPRs + 1.7 GB of scratch spill writes per dispatch.
// ---------------------------------------------------------------------------

#define WS_ALIGN(x) (((x) + 255) & ~(size_t)255)

__global__ void k_zero_int(int* p, int n) {
  int i = blockIdx.x * blockDim.x + threadIdx.x;
  if (i < n) p[i] = 0;
}

__global__ void k_count(const int* __restrict__ dst, int E, int* __restrict__ cnt) {
  int e = blockIdx.x * blockDim.x + threadIdx.x;
  if (e < E) atomicAdd(&cnt[dst[e]], 1);
}

__global__ void k_dinv(const int* __restrict__ cnt, float* __restrict__ dinv,
                       int* __restrict__ cursor, int n) {
  int i = blockIdx.x * blockDim.x + threadIdx.x;
  if (i < n) {
    dinv[i] = rsqrtf((float)(cnt[i] + 1));  // +1 = self-loop; always > 0
    cursor[i] = 0;
  }
}

// Block-wise exclusive scan (Hillis-Steele in LDS), 1024 elems/block
__global__ __launch_bounds__(1024) void k_scan1(const int* __restrict__ cnt, int n,
                                                int* __restrict__ rs, int* __restrict__ bsum) {
  __shared__ int tmp[1024];
  int tid = threadIdx.x;
  int i = blockIdx.x * 1024 + tid;
  int v = (i < n) ? cnt[i] : 0;
  tmp[tid] = v;
  __syncthreads();
  for (int off = 1; off < 1024; off <<= 1) {
    int t = (tid >= off) ? tmp[tid - off] : 0;
    __syncthreads();
    tmp[tid] += t;
    __syncthreads();
  }
  if (i < n) rs[i] = tmp[tid] - v;           // exclusive
  if (tid == 1023) bsum[blockIdx.x] = tmp[1023];
}

// Single-block scan of the (<=128) block sums
__global__ __launch_bounds__(128) void k_scan2(int* bsum, int nb) {
  __shared__ int tmp[128];
  int tid = threadIdx.x;
  int v = (tid < nb) ? bsum[tid] : 0;
  tmp[tid] = v;
  __syncthreads();
  for (int off = 1; off < 128; off <<= 1) {
    int t = (tid >= off) ? tmp[tid - off] : 0;
    __syncthreads();
    tmp[tid] += t;
    __syncthreads();
  }
  if (tid < nb) bsum[tid] = tmp[tid] - v;    // exclusive
}

__global__ void k_scan3(int* rs, const int* __restrict__ bsum, int n, int E) {
  int i = blockIdx.x * blockDim.x + threadIdx.x;
  if (i < n) rs[i] += bsum[i >> 10];
  if (i == 0) rs[n] = E;
}

__global__ void k_fill(const int* __restrict__ src, const int* __restrict__ dst, int E,
                       const int* __restrict__ rs, int* __restrict__ cursor,
                       const float* __restrict__ dinv,
                       int* __restrict__ csrc, float* __restrict__ cw) {
  int e = blockIdx.x * blockDim.x + threadIdx.x;
  if (e < E) {
    int s = src[e], d = dst[e];
    int pos = atomicAdd(&cursor[d], 1);
    int idx = rs[d] + pos;
    csrc[idx] = s;
    cw[idx] = dinv[s] * dinv[d];
  }
}

// C[N,128] = X[N,128] @ W[128,128] (+bias). W staged in LDS (64 KB).
// Block: 512 threads -> 64 rows x 128 cols; thread = 4 rows x 4 cols.
// k-loop unroll capped at 2: R1's full unroll spilled 1.7 GB of scratch.
__global__ __launch_bounds__(512) void k_gemm128(const float* __restrict__ X,
                                                 const float* __restrict__ W,
                                                 const float* __restrict__ bias,
                                                 float* __restrict__ Y, int n) {
  __shared__ float4 sW4[128 * 32];
  const float4* W4 = (const float4*)W;
  for (int i = threadIdx.x; i < 128 * 32; i += 512) sW4[i] = W4[i];
  __syncthreads();

  int tx = threadIdx.x & 31;   // col group: cols [4*tx, 4*tx+3]
  int ty = threadIdx.x >> 5;   // 0..15 -> rows [r0, r0+3]
  int r0 = blockIdx.x * 64 + ty * 4;
  int rc[4];
#pragma unroll
  for (int rr = 0; rr < 4; rr++) { int r = r0 + rr; rc[rr] = (r < n) ? r : (n - 1); }

  const float4* X4 = (const float4*)X;
  float acc[4][4] = {};
#pragma unroll 2
  for (int k4 = 0; k4 < 32; k4++) {
    float4 xv[4];
#pragma unroll
    for (int rr = 0; rr < 4; rr++) xv[rr] = X4[(size_t)rc[rr] * 32 + k4];
#pragma unroll
    for (int kk = 0; kk < 4; kk++) {
      float4 w = sW4[(k4 * 4 + kk) * 32 + tx];
#pragma unroll
      for (int rr = 0; rr < 4; rr++) {
        float xs = (kk == 0) ? xv[rr].x : (kk == 1) ? xv[rr].y : (kk == 2) ? xv[rr].z : xv[rr].w;
        acc[rr][0] = fmaf(xs, w.x, acc[rr][0]);
        acc[rr][1] = fmaf(xs, w.y, acc[rr][1]);
        acc[rr][2] = fmaf(xs, w.z, acc[rr][2]);
        acc[rr][3] = fmaf(xs, w.w, acc[rr][3]);
      }
    }
  }

  float4 b4 = make_float4(0.f, 0.f, 0.f, 0.f);
  if (bias) b4 = ((const float4*)bias)[tx];
#pragma unroll
  for (int rr = 0; rr < 4; rr++) {
    int r = r0 + rr;
    if (r < n) {
      float4 o;
      o.x = acc[rr][0] + b4.x; o.y = acc[rr][1] + b4.y;
      o.z = acc[rr][2] + b4.z; o.w = acc[rr][3] + b4.w;
      ((float4*)Y)[(size_t)r * 32 + tx] = o;
    }
  }
}

// Gather aggregation: one wave (64 lanes) per node, lane -> 2 columns (float2).
// out = relu( sum_{e: dst=node} w_e * H[src_e] + dinv^2 * H[node] + bias ) [+ resid]
__global__ __launch_bounds__(256) void k_agg(const float* __restrict__ H,
                                             const int* __restrict__ rs,
                                             const int* __restrict__ csrc,
                                             const float* __restrict__ cw,
                                             const float* __restrict__ dinv,
                                             const float* __restrict__ bias,
                                             const float* __restrict__ resid,
                                             float* __restrict__ out, int n) {
  int gid = blockIdx.x * 256 + threadIdx.x;
  int node = gid >> 6;
  int lane = threadIdx.x & 63;
  if (node >= n) return;

  const float2* H2 = (const float2*)H;
  float di = dinv[node];
  float ws = di * di;
  float2 hv = H2[(size_t)node * 64 + lane];
  float ax = hv.x * ws, ay = hv.y * ws;

  int beg = rs[node], end = rs[node + 1];
  for (int j = beg; j < end; j++) {
    int s = csrc[j];           // wave-uniform
    float w = cw[j];           // wave-uniform
    float2 h2 = H2[(size_t)s * 64 + lane];   // 512B coalesced gather
    ax = fmaf(w, h2.x, ax);
    ay = fmaf(w, h2.y, ay);
  }

  float2 b2 = ((const float2*)bias)[lane];
  ax += b2.x; ay += b2.y;
  ax = fmaxf(ax, 0.f); ay = fmaxf(ay, 0.f);
  if (resid) {
    float2 r2 = ((const float2*)resid)[(size_t)node * 64 + lane];
    ax += r2.x; ay += r2.y;
  }
  float2 o; o.x = ax; o.y = ay;
  ((float2*)out)[(size_t)node * 64 + lane] = o;
}

extern "C" void kernel_launch(void* const* d_in, const int* in_sizes, int n_in,
                              void* d_out, int out_size, void* d_ws, size_t ws_size,
                              hipStream_t stream) {
  const float* x  = (const float*)d_in[0];
  const int* edges = (const int*)d_in[1];
  const float* W0 = (const float*)d_in[2];
  const float* b0 = (const float*)d_in[3];
  const float* W1 = (const float*)d_in[4];
  const float* b1 = (const float*)d_in[5];
  const float* W2 = (const float*)d_in[6];
  const float* b2 = (const float*)d_in[7];
  const float* Wr = (const float*)d_in[8];
  const float* br = (const float*)d_in[9];

  int N = in_sizes[0] / 128;
  int E = in_sizes[1] / 2;
  const int* src = edges;
  const int* dst = edges + E;

  char* ws = (char*)d_ws;
  size_t off = 0;
  auto alloc = [&](size_t bytes) -> void* {
    void* p = ws + off; off = WS_ALIGN(off + bytes); return p;
  };
  int*   cnt    = (int*)  alloc((size_t)N * 4);
  int*   cursor = (int*)  alloc((size_t)N * 4);
  float* dinv   = (float*)alloc((size_t)N * 4);
  int*   rs     = (int*)  alloc((size_t)(N + 1) * 4);
  int*   bsum   = (int*)  alloc(1024);
  int*   csrc   = (int*)  alloc((size_t)E * 4);
  float* cw     = (float*)alloc((size_t)E * 4);
  float* A      = (float*)alloc((size_t)N * 128 * 4);
  float* R      = (float*)alloc((size_t)N * 128 * 4);
  (void)ws_size; (void)n_in; (void)out_size;

  int nb1 = (N + 1023) / 1024;   // 98 for N=100000 (must be <= 128)

  // ---- normalization + CSR build ----
  k_zero_int<<<(N + 255) / 256, 256, 0, stream>>>(cnt, N);
  k_count  <<<(E + 255) / 256, 256, 0, stream>>>(dst, E, cnt);
  k_dinv   <<<(N + 255) / 256, 256, 0, stream>>>(cnt, dinv, cursor, N);
  k_scan1  <<<nb1, 1024, 0, stream>>>(cnt, N, rs, bsum);
  k_scan2  <<<1, 128, 0, stream>>>(bsum, nb1);
  k_scan3  <<<(N + 255) / 256, 256, 0, stream>>>(rs, bsum, N, E);
  k_fill   <<<(E + 255) / 256, 256, 0, stream>>>(src, dst, E, rs, cursor, dinv, csrc, cw);

  // ---- GCN layers ----
  float* OUT = (float*)d_out;
  int gb = (N + 63) / 64;
  int ab = (N * 64 + 255) / 256;  // one wave per node

  k_gemm128<<<gb, 512, 0, stream>>>(x, Wr, br, R, N);              // residual
  k_gemm128<<<gb, 512, 0, stream>>>(x, W0, nullptr, A, N);
  k_agg    <<<ab, 256, 0, stream>>>(A, rs, csrc, cw, dinv, b0, R, OUT, N);   // layer 0
  k_gemm128<<<gb, 512, 0, stream>>>(OUT, W1, nullptr, A, N);
  k_agg    <<<ab, 256, 0, stream>>>(A, rs, csrc, cw, dinv, b1, nullptr, R, N); // layer 1
  k_gemm128<<<gb, 512, 0, stream>>>(R, W2, nullptr, A, N);
  k_agg    <<<ab, 256, 0, stream>>>(A, rs, csrc, cw, dinv, b2, nullptr, OUT, N); // layer 2
}

// Round 3
// 918.517 us; speedup vs baseline: 8.2333x; 1.1521x over previous
//
#include <hip/hip_runtime.h>
#include <hip/hip_bf16.h>
#include <cstdint>

// ---------------------------------------------------------------------------
// 3-layer GCN on MI355X.
// Pipeline per call (all on `stream`, graph-capture safe):
//   1. cnt[i]   = in-degree (atomics over E)
//   2. dinv[i]  = rsqrt(cnt+1)  (self-loop included), cursor=0
//   3. rs[]     = exclusive scan of cnt (3-kernel scan), rs[N]=E
//   4. CSR fill: edges grouped by dst, weight w = dinv[src]*dinv[dst]
//   5. R = x@Wr + br        (residual GEMM)
//   6. A = x@W0;  OUT  = relu(S(A)+b0) + R      (S = normalized adjacency)
//   7. A = OUT@W1; R   = relu(S(A)+b1)
//   8. A = R@W2;  OUT  = relu(S(A)+b2)
// Aggregation is gather-style: one wave per node, no float atomics.
//
// R1: GEMM full k-unroll spilled (256 VGPR, 1.7 GB scratch writes) -> tile
//     4x4, unroll 2.  R2: agg was latency-bound (1 gather in flight/wave,
//     2.75 TB/s, VALU 14%) -> edge loop unrolled x8 for MLP; GEMM unroll 2->4.
// ---------------------------------------------------------------------------

#define WS_ALIGN(x) (((x) + 255) & ~(size_t)255)

__global__ void k_zero_int(int* p, int n) {
  int i = blockIdx.x * blockDim.x + threadIdx.x;
  if (i < n) p[i] = 0;
}

__global__ void k_count(const int* __restrict__ dst, int E, int* __restrict__ cnt) {
  int e = blockIdx.x * blockDim.x + threadIdx.x;
  if (e < E) atomicAdd(&cnt[dst[e]], 1);
}

__global__ void k_dinv(const int* __restrict__ cnt, float* __restrict__ dinv,
                       int* __restrict__ cursor, int n) {
  int i = blockIdx.x * blockDim.x + threadIdx.x;
  if (i < n) {
    dinv[i] = rsqrtf((float)(cnt[i] + 1));  // +1 = self-loop; always > 0
    cursor[i] = 0;
  }
}

// Block-wise exclusive scan (Hillis-Steele in LDS), 1024 elems/block
__global__ __launch_bounds__(1024) void k_scan1(const int* __restrict__ cnt, int n,
                                                int* __restrict__ rs, int* __restrict__ bsum) {
  __shared__ int tmp[1024];
  int tid = threadIdx.x;
  int i = blockIdx.x * 1024 + tid;
  int v = (i < n) ? cnt[i] : 0;
  tmp[tid] = v;
  __syncthreads();
  for (int off = 1; off < 1024; off <<= 1) {
    int t = (tid >= off) ? tmp[tid - off] : 0;
    __syncthreads();
    tmp[tid] += t;
    __syncthreads();
  }
  if (i < n) rs[i] = tmp[tid] - v;           // exclusive
  if (tid == 1023) bsum[blockIdx.x] = tmp[1023];
}

// Single-block scan of the (<=128) block sums
__global__ __launch_bounds__(128) void k_scan2(int* bsum, int nb) {
  __shared__ int tmp[128];
  int tid = threadIdx.x;
  int v = (tid < nb) ? bsum[tid] : 0;
  tmp[tid] = v;
  __syncthreads();
  for (int off = 1; off < 128; off <<= 1) {
    int t = (tid >= off) ? tmp[tid - off] : 0;
    __syncthreads();
    tmp[tid] += t;
    __syncthreads();
  }
  if (tid < nb) bsum[tid] = tmp[tid] - v;    // exclusive
}

__global__ void k_scan3(int* rs, const int* __restrict__ bsum, int n, int E) {
  int i = blockIdx.x * blockDim.x + threadIdx.x;
  if (i < n) rs[i] += bsum[i >> 10];
  if (i == 0) rs[n] = E;
}

__global__ void k_fill(const int* __restrict__ src, const int* __restrict__ dst, int E,
                       const int* __restrict__ rs, int* __restrict__ cursor,
                       const float* __restrict__ dinv,
                       int* __restrict__ csrc, float* __restrict__ cw) {
  int e = blockIdx.x * blockDim.x + threadIdx.x;
  if (e < E) {
    int s = src[e], d = dst[e];
    int pos = atomicAdd(&cursor[d], 1);
    int idx = rs[d] + pos;
    csrc[idx] = s;
    cw[idx] = dinv[s] * dinv[d];
  }
}

// C[N,128] = X[N,128] @ W[128,128] (+bias). W staged in LDS (64 KB).
// Block: 512 threads -> 64 rows x 128 cols; thread = 4 rows x 4 cols.
// k-loop unroll 4: deep enough X-load pipeline, shallow enough to not spill
// (R1's full 32x unroll hit 256 VGPR + scratch).
__global__ __launch_bounds__(512) void k_gemm128(const float* __restrict__ X,
                                                 const float* __restrict__ W,
                                                 const float* __restrict__ bias,
                                                 float* __restrict__ Y, int n) {
  __shared__ float4 sW4[128 * 32];
  const float4* W4 = (const float4*)W;
  for (int i = threadIdx.x; i < 128 * 32; i += 512) sW4[i] = W4[i];
  __syncthreads();

  int tx = threadIdx.x & 31;   // col group: cols [4*tx, 4*tx+3]
  int ty = threadIdx.x >> 5;   // 0..15 -> rows [r0, r0+3]
  int r0 = blockIdx.x * 64 + ty * 4;
  int rc[4];
#pragma unroll
  for (int rr = 0; rr < 4; rr++) { int r = r0 + rr; rc[rr] = (r < n) ? r : (n - 1); }

  const float4* X4 = (const float4*)X;
  float acc[4][4] = {};
#pragma unroll 4
  for (int k4 = 0; k4 < 32; k4++) {
    float4 xv[4];
#pragma unroll
    for (int rr = 0; rr < 4; rr++) xv[rr] = X4[(size_t)rc[rr] * 32 + k4];
#pragma unroll
    for (int kk = 0; kk < 4; kk++) {
      float4 w = sW4[(k4 * 4 + kk) * 32 + tx];
#pragma unroll
      for (int rr = 0; rr < 4; rr++) {
        float xs = (kk == 0) ? xv[rr].x : (kk == 1) ? xv[rr].y : (kk == 2) ? xv[rr].z : xv[rr].w;
        acc[rr][0] = fmaf(xs, w.x, acc[rr][0]);
        acc[rr][1] = fmaf(xs, w.y, acc[rr][1]);
        acc[rr][2] = fmaf(xs, w.z, acc[rr][2]);
        acc[rr][3] = fmaf(xs, w.w, acc[rr][3]);
      }
    }
  }

  float4 b4 = make_float4(0.f, 0.f, 0.f, 0.f);
  if (bias) b4 = ((const float4*)bias)[tx];
#pragma unroll
  for (int rr = 0; rr < 4; rr++) {
    int r = r0 + rr;
    if (r < n) {
      float4 o;
      o.x = acc[rr][0] + b4.x; o.y = acc[rr][1] + b4.y;
      o.z = acc[rr][2] + b4.z; o.w = acc[rr][3] + b4.w;
      ((float4*)Y)[(size_t)r * 32 + tx] = o;
    }
  }
}

// Gather aggregation: one wave (64 lanes) per node, lane -> 2 columns (float2).
// out = relu( sum_{e: dst=node} w_e * H[src_e] + dinv^2 * H[node] + bias ) [+ resid]
// Edge loop unrolled x8: 8 independent 512B gathers in flight per wave
// (R2: single-gather-in-flight was latency-bound at 2.75 TB/s, VALU 14%).
__global__ __launch_bounds__(256) void k_agg(const float* __restrict__ H,
                                             const int* __restrict__ rs,
                                             const int* __restrict__ csrc,
                                             const float* __restrict__ cw,
                                             const float* __restrict__ dinv,
                                             const float* __restrict__ bias,
                                             const float* __restrict__ resid,
                                             float* __restrict__ out, int n) {
  int gid = blockIdx.x * 256 + threadIdx.x;
  int node = gid >> 6;
  int lane = threadIdx.x & 63;
  if (node >= n) return;

  const float2* H2 = (const float2*)H;
  float di = dinv[node];
  float ws = di * di;
  float2 hv = H2[(size_t)node * 64 + lane];
  float ax = hv.x * ws, ay = hv.y * ws;

  int j = rs[node], end = rs[node + 1];

  for (; j + 8 <= end; j += 8) {
    int   s0 = csrc[j+0], s1 = csrc[j+1], s2 = csrc[j+2], s3 = csrc[j+3];
    int   s4 = csrc[j+4], s5 = csrc[j+5], s6 = csrc[j+6], s7 = csrc[j+7];
    float w0 = cw[j+0], w1 = cw[j+1], w2 = cw[j+2], w3 = cw[j+3];
    float w4 = cw[j+4], w5 = cw[j+5], w6 = cw[j+6], w7 = cw[j+7];
    float2 h0 = H2[(size_t)s0 * 64 + lane];
    float2 h1 = H2[(size_t)s1 * 64 + lane];
    float2 h2 = H2[(size_t)s2 * 64 + lane];
    float2 h3 = H2[(size_t)s3 * 64 + lane];
    float2 h4 = H2[(size_t)s4 * 64 + lane];
    float2 h5 = H2[(size_t)s5 * 64 + lane];
    float2 h6 = H2[(size_t)s6 * 64 + lane];
    float2 h7 = H2[(size_t)s7 * 64 + lane];
    ax = fmaf(w0, h0.x, ax); ay = fmaf(w0, h0.y, ay);
    ax = fmaf(w1, h1.x, ax); ay = fmaf(w1, h1.y, ay);
    ax = fmaf(w2, h2.x, ax); ay = fmaf(w2, h2.y, ay);
    ax = fmaf(w3, h3.x, ax); ay = fmaf(w3, h3.y, ay);
    ax = fmaf(w4, h4.x, ax); ay = fmaf(w4, h4.y, ay);
    ax = fmaf(w5, h5.x, ax); ay = fmaf(w5, h5.y, ay);
    ax = fmaf(w6, h6.x, ax); ay = fmaf(w6, h6.y, ay);
    ax = fmaf(w7, h7.x, ax); ay = fmaf(w7, h7.y, ay);
  }
  for (; j + 4 <= end; j += 4) {
    int   s0 = csrc[j+0], s1 = csrc[j+1], s2 = csrc[j+2], s3 = csrc[j+3];
    float w0 = cw[j+0], w1 = cw[j+1], w2 = cw[j+2], w3 = cw[j+3];
    float2 h0 = H2[(size_t)s0 * 64 + lane];
    float2 h1 = H2[(size_t)s1 * 64 + lane];
    float2 h2 = H2[(size_t)s2 * 64 + lane];
    float2 h3 = H2[(size_t)s3 * 64 + lane];
    ax = fmaf(w0, h0.x, ax); ay = fmaf(w0, h0.y, ay);
    ax = fmaf(w1, h1.x, ax); ay = fmaf(w1, h1.y, ay);
    ax = fmaf(w2, h2.x, ax); ay = fmaf(w2, h2.y, ay);
    ax = fmaf(w3, h3.x, ax); ay = fmaf(w3, h3.y, ay);
  }
  for (; j < end; j++) {
    int s = csrc[j];
    float w = cw[j];
    float2 h2 = H2[(size_t)s * 64 + lane];
    ax = fmaf(w, h2.x, ax);
    ay = fmaf(w, h2.y, ay);
  }

  float2 b2 = ((const float2*)bias)[lane];
  ax += b2.x; ay += b2.y;
  ax = fmaxf(ax, 0.f); ay = fmaxf(ay, 0.f);
  if (resid) {
    float2 r2 = ((const float2*)resid)[(size_t)node * 64 + lane];
    ax += r2.x; ay += r2.y;
  }
  float2 o; o.x = ax; o.y = ay;
  ((float2*)out)[(size_t)node * 64 + lane] = o;
}

extern "C" void kernel_launch(void* const* d_in, const int* in_sizes, int n_in,
                              void* d_out, int out_size, void* d_ws, size_t ws_size,
                              hipStream_t stream) {
  const float* x  = (const float*)d_in[0];
  const int* edges = (const int*)d_in[1];
  const float* W0 = (const float*)d_in[2];
  const float* b0 = (const float*)d_in[3];
  const float* W1 = (const float*)d_in[4];
  const float* b1 = (const float*)d_in[5];
  const float* W2 = (const float*)d_in[6];
  const float* b2 = (const float*)d_in[7];
  const float* Wr = (const float*)d_in[8];
  const float* br = (const float*)d_in[9];

  int N = in_sizes[0] / 128;
  int E = in_sizes[1] / 2;
  const int* src = edges;
  const int* dst = edges + E;

  char* ws = (char*)d_ws;
  size_t off = 0;
  auto alloc = [&](size_t bytes) -> void* {
    void* p = ws + off; off = WS_ALIGN(off + bytes); return p;
  };
  int*   cnt    = (int*)  alloc((size_t)N * 4);
  int*   cursor = (int*)  alloc((size_t)N * 4);
  float* dinv   = (float*)alloc((size_t)N * 4);
  int*   rs     = (int*)  alloc((size_t)(N + 1) * 4);
  int*   bsum   = (int*)  alloc(1024);
  int*   csrc   = (int*)  alloc((size_t)E * 4);
  float* cw     = (float*)alloc((size_t)E * 4);
  float* A      = (float*)alloc((size_t)N * 128 * 4);
  float* R      = (float*)alloc((size_t)N * 128 * 4);
  (void)ws_size; (void)n_in; (void)out_size;

  int nb1 = (N + 1023) / 1024;   // 98 for N=100000 (must be <= 128)

  // ---- normalization + CSR build ----
  k_zero_int<<<(N + 255) / 256, 256, 0, stream>>>(cnt, N);
  k_count  <<<(E + 255) / 256, 256, 0, stream>>>(dst, E, cnt);
  k_dinv   <<<(N + 255) / 256, 256, 0, stream>>>(cnt, dinv, cursor, N);
  k_scan1  <<<nb1, 1024, 0, stream>>>(cnt, N, rs, bsum);
  k_scan2  <<<1, 128, 0, stream>>>(bsum, nb1);
  k_scan3  <<<(N + 255) / 256, 256, 0, stream>>>(rs, bsum, N, E);
  k_fill   <<<(E + 255) / 256, 256, 0, stream>>>(src, dst, E, rs, cursor, dinv, csrc, cw);

  // ---- GCN layers ----
  float* OUT = (float*)d_out;
  int gb = (N + 63) / 64;
  int ab = (N * 64 + 255) / 256;  // one wave per node

  k_gemm128<<<gb, 512, 0, stream>>>(x, Wr, br, R, N);              // residual
  k_gemm128<<<gb, 512, 0, stream>>>(x, W0, nullptr, A, N);
  k_agg    <<<ab, 256, 0, stream>>>(A, rs, csrc, cw, dinv, b0, R, OUT, N);   // layer 0
  k_gemm128<<<gb, 512, 0, stream>>>(OUT, W1, nullptr, A, N);
  k_agg    <<<ab, 256, 0, stream>>>(A, rs, csrc, cw, dinv, b1, nullptr, R, N); // layer 1
  k_gemm128<<<gb, 512, 0, stream>>>(R, W2, nullptr, A, N);
  k_agg    <<<ab, 256, 0, stream>>>(A, rs, csrc, cw, dinv, b2, nullptr, OUT, N); // layer 2
}

// Round 4
// 904.790 us; speedup vs baseline: 8.3582x; 1.0152x over previous
//
#include <hip/hip_runtime.h>
#include <hip/hip_bf16.h>
#include <cstdint>

// ---------------------------------------------------------------------------
// 3-layer GCN on MI355X.
// Pipeline per call (all on `stream`, graph-capture safe):
//   1. cnt[i]   = in-degree (atomics over E)
//   2. dinv[i]  = rsqrt(cnt+1)  (self-loop included), cursor=0
//   3. rs[]     = exclusive scan of cnt (3-kernel scan), rs[N]=E
//   4. CSR fill: edges grouped by dst, packed int2 {src, bits(w)},
//      w = dinv[src]*dinv[dst]
//   5. R = x@Wr + br        (residual GEMM)
//   6. A = x@W0;  OUT  = relu(S(A)+b0) + R      (S = normalized adjacency)
//   7. A = OUT@W1; R   = relu(S(A)+b1)
//   8. A = R@W2;  OUT  = relu(S(A)+b2)
// Aggregation is gather-style: one wave per node, no float atomics.
//
// R1: GEMM full k-unroll spilled (256 VGPR, 1.7 GB scratch) -> 4x4 tile.
// R2: agg latency-bound (1 gather in flight) -> MLP 8.
// R3: k_fill scatter RMW (155 MB writes for 12.8 MB payload) -> single 8B
//     packed store; agg MLP 8->16; GEMM 64x64 tile / 32 KB LDS -> 5 blk/CU.
// ---------------------------------------------------------------------------

#define WS_ALIGN(x) (((x) + 255) & ~(size_t)255)

__global__ void k_zero_int(int* p, int n) {
  int i = blockIdx.x * blockDim.x + threadIdx.x;
  if (i < n) p[i] = 0;
}

__global__ void k_count(const int* __restrict__ dst, int E, int* __restrict__ cnt) {
  int e = blockIdx.x * blockDim.x + threadIdx.x;
  if (e < E) atomicAdd(&cnt[dst[e]], 1);
}

__global__ void k_dinv(const int* __restrict__ cnt, float* __restrict__ dinv,
                       int* __restrict__ cursor, int n) {
  int i = blockIdx.x * blockDim.x + threadIdx.x;
  if (i < n) {
    dinv[i] = rsqrtf((float)(cnt[i] + 1));  // +1 = self-loop; always > 0
    cursor[i] = 0;
  }
}

// Block-wise exclusive scan (Hillis-Steele in LDS), 1024 elems/block
__global__ __launch_bounds__(1024) void k_scan1(const int* __restrict__ cnt, int n,
                                                int* __restrict__ rs, int* __restrict__ bsum) {
  __shared__ int tmp[1024];
  int tid = threadIdx.x;
  int i = blockIdx.x * 1024 + tid;
  int v = (i < n) ? cnt[i] : 0;
  tmp[tid] = v;
  __syncthreads();
  for (int off = 1; off < 1024; off <<= 1) {
    int t = (tid >= off) ? tmp[tid - off] : 0;
    __syncthreads();
    tmp[tid] += t;
    __syncthreads();
  }
  if (i < n) rs[i] = tmp[tid] - v;           // exclusive
  if (tid == 1023) bsum[blockIdx.x] = tmp[1023];
}

// Single-block scan of the (<=128) block sums
__global__ __launch_bounds__(128) void k_scan2(int* bsum, int nb) {
  __shared__ int tmp[128];
  int tid = threadIdx.x;
  int v = (tid < nb) ? bsum[tid] : 0;
  tmp[tid] = v;
  __syncthreads();
  for (int off = 1; off < 128; off <<= 1) {
    int t = (tid >= off) ? tmp[tid - off] : 0;
    __syncthreads();
    tmp[tid] += t;
    __syncthreads();
  }
  if (tid < nb) bsum[tid] = tmp[tid] - v;    // exclusive
}

__global__ void k_scan3(int* rs, const int* __restrict__ bsum, int n, int E) {
  int i = blockIdx.x * blockDim.x + threadIdx.x;
  if (i < n) rs[i] += bsum[i >> 10];
  if (i == 0) rs[n] = E;
}

// Packed fill: one 8 B scattered store per edge {src, bits(w)}.
__global__ void k_fill(const int* __restrict__ src, const int* __restrict__ dst, int E,
                       const int* __restrict__ rs, int* __restrict__ cursor,
                       const float* __restrict__ dinv,
                       int2* __restrict__ epk) {
  int e = blockIdx.x * blockDim.x + threadIdx.x;
  if (e < E) {
    int s = src[e], d = dst[e];
    int pos = atomicAdd(&cursor[d], 1);
    int idx = rs[d] + pos;
    int2 v;
    v.x = s;
    v.y = __float_as_int(dinv[s] * dinv[d]);
    epk[idx] = v;
  }
}

// C[N,128] = X[N,128] @ W[128,128] (+bias). 64x64 tile, 256 threads,
// thread = 4 rows x 4 cols. W col-slice (128k x 64) in 32 KB LDS -> 5 blk/CU.
// Grid x = 2 * row_blocks; low bit = column block.
__global__ __launch_bounds__(256) void k_gemm128(const float* __restrict__ X,
                                                 const float* __restrict__ W,
                                                 const float* __restrict__ bias,
                                                 float* __restrict__ Y, int n) {
  __shared__ float4 sW4[128 * 16];
  int cb = blockIdx.x & 1;         // column block: cols [cb*64, cb*64+63]
  int rb = blockIdx.x >> 1;

  const float4* W4 = (const float4*)W;
  for (int i = threadIdx.x; i < 128 * 16; i += 256) {
    int k = i >> 4, c4 = i & 15;
    sW4[i] = W4[k * 32 + cb * 16 + c4];
  }
  __syncthreads();

  int tx = threadIdx.x & 15;   // col group within slice: cols [4*tx, 4*tx+3]
  int ty = threadIdx.x >> 4;   // 0..15 -> rows [r0, r0+3]
  int r0 = rb * 64 + ty * 4;
  int rc[4];
#pragma unroll
  for (int rr = 0; rr < 4; rr++) { int r = r0 + rr; rc[rr] = (r < n) ? r : (n - 1); }

  const float4* X4 = (const float4*)X;
  float acc[4][4] = {};
#pragma unroll 4
  for (int k4 = 0; k4 < 32; k4++) {
    float4 xv[4];
#pragma unroll
    for (int rr = 0; rr < 4; rr++) xv[rr] = X4[(size_t)rc[rr] * 32 + k4];
#pragma unroll
    for (int kk = 0; kk < 4; kk++) {
      float4 w = sW4[(k4 * 4 + kk) * 16 + tx];
#pragma unroll
      for (int rr = 0; rr < 4; rr++) {
        float xs = (kk == 0) ? xv[rr].x : (kk == 1) ? xv[rr].y : (kk == 2) ? xv[rr].z : xv[rr].w;
        acc[rr][0] = fmaf(xs, w.x, acc[rr][0]);
        acc[rr][1] = fmaf(xs, w.y, acc[rr][1]);
        acc[rr][2] = fmaf(xs, w.z, acc[rr][2]);
        acc[rr][3] = fmaf(xs, w.w, acc[rr][3]);
      }
    }
  }

  float4 b4 = make_float4(0.f, 0.f, 0.f, 0.f);
  if (bias) b4 = ((const float4*)bias)[cb * 16 + tx];
#pragma unroll
  for (int rr = 0; rr < 4; rr++) {
    int r = r0 + rr;
    if (r < n) {
      float4 o;
      o.x = acc[rr][0] + b4.x; o.y = acc[rr][1] + b4.y;
      o.z = acc[rr][2] + b4.z; o.w = acc[rr][3] + b4.w;
      ((float4*)Y)[(size_t)r * 32 + cb * 16 + tx] = o;
    }
  }
}

// Gather aggregation: one wave (64 lanes) per node, lane -> 2 columns (float2).
// out = relu( sum_{e: dst=node} w_e * H[src_e] + dinv^2 * H[node] + bias ) [+ resid]
// Edge loop unrolled x16: 16 independent 512B gathers in flight per wave.
__global__ __launch_bounds__(256) void k_agg(const float* __restrict__ H,
                                             const int* __restrict__ rs,
                                             const int2* __restrict__ epk,
                                             const float* __restrict__ dinv,
                                             const float* __restrict__ bias,
                                             const float* __restrict__ resid,
                                             float* __restrict__ out, int n) {
  int gid = blockIdx.x * 256 + threadIdx.x;
  int node = gid >> 6;
  int lane = threadIdx.x & 63;
  if (node >= n) return;

  const float2* H2 = (const float2*)H;
  float di = dinv[node];
  float ws = di * di;
  float2 hv = H2[(size_t)node * 64 + lane];
  float ax = hv.x * ws, ay = hv.y * ws;

  int j = rs[node], end = rs[node + 1];

  for (; j + 16 <= end; j += 16) {
    int2 e[16];
#pragma unroll
    for (int u = 0; u < 16; u++) e[u] = epk[j + u];
    float2 h[16];
#pragma unroll
    for (int u = 0; u < 16; u++) h[u] = H2[(size_t)e[u].x * 64 + lane];
#pragma unroll
    for (int u = 0; u < 16; u++) {
      float w = __int_as_float(e[u].y);
      ax = fmaf(w, h[u].x, ax);
      ay = fmaf(w, h[u].y, ay);
    }
  }
  for (; j + 4 <= end; j += 4) {
    int2 e[4];
#pragma unroll
    for (int u = 0; u < 4; u++) e[u] = epk[j + u];
    float2 h[4];
#pragma unroll
    for (int u = 0; u < 4; u++) h[u] = H2[(size_t)e[u].x * 64 + lane];
#pragma unroll
    for (int u = 0; u < 4; u++) {
      float w = __int_as_float(e[u].y);
      ax = fmaf(w, h[u].x, ax);
      ay = fmaf(w, h[u].y, ay);
    }
  }
  for (; j < end; j++) {
    int2 e = epk[j];
    float w = __int_as_float(e.y);
    float2 h2 = H2[(size_t)e.x * 64 + lane];
    ax = fmaf(w, h2.x, ax);
    ay = fmaf(w, h2.y, ay);
  }

  float2 b2 = ((const float2*)bias)[lane];
  ax += b2.x; ay += b2.y;
  ax = fmaxf(ax, 0.f); ay = fmaxf(ay, 0.f);
  if (resid) {
    float2 r2 = ((const float2*)resid)[(size_t)node * 64 + lane];
    ax += r2.x; ay += r2.y;
  }
  float2 o; o.x = ax; o.y = ay;
  ((float2*)out)[(size_t)node * 64 + lane] = o;
}

extern "C" void kernel_launch(void* const* d_in, const int* in_sizes, int n_in,
                              void* d_out, int out_size, void* d_ws, size_t ws_size,
                              hipStream_t stream) {
  const float* x  = (const float*)d_in[0];
  const int* edges = (const int*)d_in[1];
  const float* W0 = (const float*)d_in[2];
  const float* b0 = (const float*)d_in[3];
  const float* W1 = (const float*)d_in[4];
  const float* b1 = (const float*)d_in[5];
  const float* W2 = (const float*)d_in[6];
  const float* b2 = (const float*)d_in[7];
  const float* Wr = (const float*)d_in[8];
  const float* br = (const float*)d_in[9];

  int N = in_sizes[0] / 128;
  int E = in_sizes[1] / 2;
  const int* src = edges;
  const int* dst = edges + E;

  char* ws = (char*)d_ws;
  size_t off = 0;
  auto alloc = [&](size_t bytes) -> void* {
    void* p = ws + off; off = WS_ALIGN(off + bytes); return p;
  };
  int*   cnt    = (int*)  alloc((size_t)N * 4);
  int*   cursor = (int*)  alloc((size_t)N * 4);
  float* dinv   = (float*)alloc((size_t)N * 4);
  int*   rs     = (int*)  alloc((size_t)(N + 1) * 4);
  int*   bsum   = (int*)  alloc(1024);
  int2*  epk    = (int2*) alloc((size_t)E * 8);
  float* A      = (float*)alloc((size_t)N * 128 * 4);
  float* R      = (float*)alloc((size_t)N * 128 * 4);
  (void)ws_size; (void)n_in; (void)out_size;

  int nb1 = (N + 1023) / 1024;   // 98 for N=100000 (must be <= 128)

  // ---- normalization + CSR build ----
  k_zero_int<<<(N + 255) / 256, 256, 0, stream>>>(cnt, N);
  k_count  <<<(E + 255) / 256, 256, 0, stream>>>(dst, E, cnt);
  k_dinv   <<<(N + 255) / 256, 256, 0, stream>>>(cnt, dinv, cursor, N);
  k_scan1  <<<nb1, 1024, 0, stream>>>(cnt, N, rs, bsum);
  k_scan2  <<<1, 128, 0, stream>>>(bsum, nb1);
  k_scan3  <<<(N + 255) / 256, 256, 0, stream>>>(rs, bsum, N, E);
  k_fill   <<<(E + 255) / 256, 256, 0, stream>>>(src, dst, E, rs, cursor, dinv, epk);

  // ---- GCN layers ----
  float* OUT = (float*)d_out;
  int gb = 2 * ((N + 63) / 64);   // x2: column blocks
  int ab = (N * 64 + 255) / 256;  // one wave per node

  k_gemm128<<<gb, 256, 0, stream>>>(x, Wr, br, R, N);              // residual
  k_gemm128<<<gb, 256, 0, stream>>>(x, W0, nullptr, A, N);
  k_agg    <<<ab, 256, 0, stream>>>(A, rs, epk, dinv, b0, R, OUT, N);   // layer 0
  k_gemm128<<<gb, 256, 0, stream>>>(OUT, W1, nullptr, A, N);
  k_agg    <<<ab, 256, 0, stream>>>(A, rs, epk, dinv, b1, nullptr, R, N); // layer 1
  k_gemm128<<<gb, 256, 0, stream>>>(R, W2, nullptr, A, N);
  k_agg    <<<ab, 256, 0, stream>>>(A, rs, epk, dinv, b2, nullptr, OUT, N); // layer 2
}

// Round 5
// 684.941 us; speedup vs baseline: 11.0410x; 1.3210x over previous
//
#include <hip/hip_runtime.h>
#include <hip/hip_bf16.h>
#include <cstdint>

// ---------------------------------------------------------------------------
// 3-layer GCN on MI355X — bf16 feature pipeline, f32 accumulate.
//   prep: x->bf16, W*->bf16 transposed (Wt[n][k]); CSR build (count/scan/fill)
//   R  = bf16( xb @ Wr + br )                     (MFMA GEMM)
//   A0 = bf16( xb @ W0 );  H0 = bf16(relu(S A0 + b0) + R)
//   A1 = bf16( H0 @ W1 );  H1 = bf16(relu(S A1 + b1))
//   A2 = bf16( H1 @ W2 );  out_f32 = relu(S A2 + b2)
// S = D^-1/2 (A+I) D^-1/2 applied gather-style: one wave per node, no
// float atomics; self-loop handled analytically (dinv^2 * h[node]).
//
// R1: f32 GEMM full k-unroll spilled -> 4x4 tile. R2: agg MLP 8 (latency).
// R3: packed int2 CSR (fill RMW), MLP16. R4 lesson: conditional MLP-16 loop
// rarely ran (deg~Poisson(17)) -> THIS round: predicated MLP-16 + bf16
// gathers (256B/edge) + bf16 MFMA GEMM (2.5PF path; f32 MFMA doesn't exist).
// ---------------------------------------------------------------------------

#define WS_ALIGN(x) (((x) + 255) & ~(size_t)255)

typedef __bf16 bf16x8 __attribute__((ext_vector_type(8)));
typedef float  floatx4 __attribute__((ext_vector_type(4)));

static __device__ __forceinline__ float bf_lo(unsigned u) {
  return __builtin_bit_cast(float, u << 16);
}
static __device__ __forceinline__ float bf_hi(unsigned u) {
  return __builtin_bit_cast(float, u & 0xffff0000u);
}
// f32 -> bf16 round-to-nearest-even (finite inputs only)
static __device__ __forceinline__ unsigned short f2bs(float f) {
  unsigned u = __builtin_bit_cast(unsigned, f);
  return (unsigned short)((u + 0x7fffu + ((u >> 16) & 1u)) >> 16);
}
static __device__ __forceinline__ unsigned pack2(float a, float b) {
  return (unsigned)f2bs(a) | ((unsigned)f2bs(b) << 16);
}

// ---------------- preprocessing ----------------

__global__ void k_zero_int(int* p, int n) {
  int i = blockIdx.x * blockDim.x + threadIdx.x;
  if (i < n) p[i] = 0;
}

__global__ void k_count(const int* __restrict__ dst, int E, int* __restrict__ cnt) {
  int e = blockIdx.x * blockDim.x + threadIdx.x;
  if (e < E) atomicAdd(&cnt[dst[e]], 1);
}

__global__ void k_dinv(const int* __restrict__ cnt, float* __restrict__ dinv,
                       int* __restrict__ cursor, int n) {
  int i = blockIdx.x * blockDim.x + threadIdx.x;
  if (i < n) {
    dinv[i] = rsqrtf((float)(cnt[i] + 1));  // +1 = self-loop; always > 0
    cursor[i] = 0;
  }
}

__global__ __launch_bounds__(1024) void k_scan1(const int* __restrict__ cnt, int n,
                                                int* __restrict__ rs, int* __restrict__ bsum) {
  __shared__ int tmp[1024];
  int tid = threadIdx.x;
  int i = blockIdx.x * 1024 + tid;
  int v = (i < n) ? cnt[i] : 0;
  tmp[tid] = v;
  __syncthreads();
  for (int off = 1; off < 1024; off <<= 1) {
    int t = (tid >= off) ? tmp[tid - off] : 0;
    __syncthreads();
    tmp[tid] += t;
    __syncthreads();
  }
  if (i < n) rs[i] = tmp[tid] - v;           // exclusive
  if (tid == 1023) bsum[blockIdx.x] = tmp[1023];
}

__global__ __launch_bounds__(128) void k_scan2(int* bsum, int nb) {
  __shared__ int tmp[128];
  int tid = threadIdx.x;
  int v = (tid < nb) ? bsum[tid] : 0;
  tmp[tid] = v;
  __syncthreads();
  for (int off = 1; off < 128; off <<= 1) {
    int t = (tid >= off) ? tmp[tid - off] : 0;
    __syncthreads();
    tmp[tid] += t;
    __syncthreads();
  }
  if (tid < nb) bsum[tid] = tmp[tid] - v;    // exclusive
}

__global__ void k_scan3(int* rs, const int* __restrict__ bsum, int n, int E) {
  int i = blockIdx.x * blockDim.x + threadIdx.x;
  if (i < n) rs[i] += bsum[i >> 10];
  if (i == 0) rs[n] = E;
}

// Packed fill: one 8 B scattered store per edge {src, bits(w)}.
__global__ void k_fill(const int* __restrict__ src, const int* __restrict__ dst, int E,
                       const int* __restrict__ rs, int* __restrict__ cursor,
                       const float* __restrict__ dinv,
                       int2* __restrict__ epk) {
  int e = blockIdx.x * blockDim.x + threadIdx.x;
  if (e < E) {
    int s = src[e], d = dst[e];
    int pos = atomicAdd(&cursor[d], 1);
    int idx = rs[d] + pos;
    int2 v;
    v.x = s;
    v.y = __float_as_int(dinv[s] * dinv[d]);
    epk[idx] = v;
  }
}

// x (f32) -> xb (bf16), 4 elems/thread
__global__ void k_xcvt(const float* __restrict__ x, unsigned* __restrict__ xb, int n4) {
  int i = blockIdx.x * 256 + threadIdx.x;
  if (i < n4) {
    float4 v = ((const float4*)x)[i];
    uint2 o;
    o.x = pack2(v.x, v.y);
    o.y = pack2(v.z, v.w);
    ((uint2*)xb)[i] = o;
  }
}

// W[k][n] f32 -> Wt[n][k] bf16 for all 4 weight matrices (blockIdx.y selects).
__global__ void k_wprep(const float* __restrict__ W0, const float* __restrict__ W1,
                        const float* __restrict__ W2, const float* __restrict__ Wr,
                        unsigned short* __restrict__ Wt) {
  const float* W = blockIdx.y == 0 ? W0 : blockIdx.y == 1 ? W1 : blockIdx.y == 2 ? W2 : Wr;
  unsigned short* T = Wt + (size_t)blockIdx.y * 16384;
  int i = blockIdx.x * 256 + threadIdx.x;   // i = k*128 + n, coalesced read
  int k = i >> 7, nn = i & 127;
  T[nn * 128 + k] = f2bs(W[i]);
}

// ---------------- bf16 MFMA GEMM: Y[n,128] = bf16( Xb[n,128] @ W + bias ) ---
// Wt is pre-transposed [n][k] bf16, staged in 32 KB LDS. Block = 256 thr =
// 4 waves; each wave computes a 16-row x 128-col strip with 32 MFMAs.
// B-frags (all 8 ct x 4 kc) cached in 128 VGPRs; A-frags direct from global.
// Layouts (verified, learn_hip m89/m120): A[m=lane&15][k=quad*8+j],
// B[k=quad*8+j][n=lane&15], C/D col=lane&15 row=quad*4+reg.
__global__ __launch_bounds__(256, 2) void k_gemm_mfma(
    const unsigned short* __restrict__ Xb,
    const unsigned short* __restrict__ Wt,
    const float* __restrict__ bias,
    unsigned short* __restrict__ Y,
    int n) {
  __shared__ unsigned short sWt[128 * 128];
  {
    const uint4* s4 = (const uint4*)Wt;
    uint4* d4 = (uint4*)sWt;
    for (int i = threadIdx.x; i < 2048; i += 256) d4[i] = s4[i];
  }
  __syncthreads();

  const int lane = threadIdx.x & 63;
  const int wave = threadIdx.x >> 6;
  const int l15 = lane & 15;
  const int quad = lane >> 4;
  const int rbase = blockIdx.x * 64 + wave * 16;

  const bf16x8* sW8 = (const bf16x8*)sWt;
  bf16x8 b[8][4];
#pragma unroll
  for (int ct = 0; ct < 8; ct++)
#pragma unroll
    for (int kc = 0; kc < 4; kc++)
      b[ct][kc] = sW8[(ct * 16 + l15) * 16 + kc * 4 + quad];

  int row = rbase + l15;
  row = row < n ? row : n - 1;
  const bf16x8* X8 = (const bf16x8*)Xb;
  bf16x8 a[4];
#pragma unroll
  for (int kc = 0; kc < 4; kc++)
    a[kc] = X8[(size_t)row * 16 + kc * 4 + quad];

  floatx4 acc[8];
#pragma unroll
  for (int ct = 0; ct < 8; ct++) acc[ct] = (floatx4){0.f, 0.f, 0.f, 0.f};

#pragma unroll
  for (int kc = 0; kc < 4; kc++)
#pragma unroll
    for (int ct = 0; ct < 8; ct++)
      acc[ct] = __builtin_amdgcn_mfma_f32_16x16x32_bf16(a[kc], b[ct][kc], acc[ct], 0, 0, 0);

  const int orow = rbase + quad * 4;
#pragma unroll
  for (int ct = 0; ct < 8; ct++) {
    const int c = ct * 16 + l15;
    const float bv = bias ? bias[c] : 0.f;
#pragma unroll
    for (int r4 = 0; r4 < 4; r4++) {
      int r = orow + r4;
      if (r < n) Y[(size_t)r * 128 + c] = f2bs(acc[ct][r4] + bv);
    }
  }
}

// ---------------- aggregation ----------------
// One wave per node, lane -> 2 bf16 columns (one uint). Predicated MLP-16:
// invalid lanes clamp to end-1 (dup gather = L1 hit) with weight 0, so the
// pipeline depth is ALWAYS 16 (R4's conditional loop rarely ran at deg~17).
__global__ __launch_bounds__(256) void k_agg(
    const unsigned* __restrict__ H,      // bf16x2 [n*64]
    const int* __restrict__ rs,
    const int2* __restrict__ epk,
    const float* __restrict__ dinv,
    const float* __restrict__ bias,
    const unsigned* __restrict__ resid,  // bf16x2 or null
    unsigned* __restrict__ outb,         // bf16x2 out (layers 0,1) or null
    float2* __restrict__ outf,           // f32 out (layer 2) or null
    int n) {
  int gid = blockIdx.x * 256 + threadIdx.x;
  int node = gid >> 6;
  int lane = threadIdx.x & 63;
  if (node >= n) return;

  float di = dinv[node];
  float ws = di * di;
  unsigned hv = H[(size_t)node * 64 + lane];
  float ax = bf_lo(hv) * ws, ay = bf_hi(hv) * ws;

  int beg = rs[node], end = rs[node + 1];
  for (int j0 = beg; j0 < end; j0 += 16) {
    int si[16];
    float w[16];
#pragma unroll
    for (int u = 0; u < 16; u++) {
      int jj = j0 + u;
      int2 ee = epk[jj < end ? jj : end - 1];
      si[u] = ee.x;
      w[u] = (jj < end) ? __int_as_float(ee.y) : 0.f;
    }
    unsigned h[16];
#pragma unroll
    for (int u = 0; u < 16; u++) h[u] = H[(size_t)(unsigned)si[u] * 64 + lane];
#pragma unroll
    for (int u = 0; u < 16; u++) {
      ax = fmaf(w[u], bf_lo(h[u]), ax);
      ay = fmaf(w[u], bf_hi(h[u]), ay);
    }
  }

  ax += bias[lane * 2];
  ay += bias[lane * 2 + 1];
  ax = fmaxf(ax, 0.f);
  ay = fmaxf(ay, 0.f);
  if (resid) {
    unsigned r = resid[(size_t)node * 64 + lane];
    ax += bf_lo(r);
    ay += bf_hi(r);
  }
  if (outb) {
    outb[(size_t)node * 64 + lane] = pack2(ax, ay);
  } else {
    float2 o;
    o.x = ax;
    o.y = ay;
    outf[(size_t)node * 64 + lane] = o;
  }
}

extern "C" void kernel_launch(void* const* d_in, const int* in_sizes, int n_in,
                              void* d_out, int out_size, void* d_ws, size_t ws_size,
                              hipStream_t stream) {
  const float* x  = (const float*)d_in[0];
  const int* edges = (const int*)d_in[1];
  const float* W0 = (const float*)d_in[2];
  const float* b0 = (const float*)d_in[3];
  const float* W1 = (const float*)d_in[4];
  const float* b1 = (const float*)d_in[5];
  const float* W2 = (const float*)d_in[6];
  const float* b2 = (const float*)d_in[7];
  const float* Wr = (const float*)d_in[8];
  const float* br = (const float*)d_in[9];

  int N = in_sizes[0] / 128;
  int E = in_sizes[1] / 2;
  const int* src = edges;
  const int* dst = edges + E;

  char* ws = (char*)d_ws;
  size_t off = 0;
  auto alloc = [&](size_t bytes) -> void* {
    void* p = ws + off; off = WS_ALIGN(off + bytes); return p;
  };
  int*   cnt    = (int*)  alloc((size_t)N * 4);
  int*   cursor = (int*)  alloc((size_t)N * 4);
  float* dinv   = (float*)alloc((size_t)N * 4);
  int*   rs     = (int*)  alloc((size_t)(N + 1) * 4);
  int*   bsum   = (int*)  alloc(1024);
  int2*  epk    = (int2*) alloc((size_t)E * 8);
  unsigned short* xb = (unsigned short*)alloc((size_t)N * 128 * 2);
  unsigned short* Wt = (unsigned short*)alloc((size_t)4 * 16384 * 2);
  unsigned short* A  = (unsigned short*)alloc((size_t)N * 128 * 2);
  unsigned short* Hb = (unsigned short*)alloc((size_t)N * 128 * 2);
  unsigned short* R  = (unsigned short*)alloc((size_t)N * 128 * 2);
  (void)ws_size; (void)n_in; (void)out_size;

  int nb1 = (N + 1023) / 1024;   // 98 for N=100000 (must be <= 128)

  // ---- conversions ----
  int n4 = N * 128 / 4;
  k_xcvt <<<(n4 + 255) / 256, 256, 0, stream>>>(x, (unsigned*)xb, n4);
  k_wprep<<<dim3(64, 4), 256, 0, stream>>>(W0, W1, W2, Wr, Wt);

  // ---- normalization + CSR build ----
  k_zero_int<<<(N + 255) / 256, 256, 0, stream>>>(cnt, N);
  k_count  <<<(E + 255) / 256, 256, 0, stream>>>(dst, E, cnt);
  k_dinv   <<<(N + 255) / 256, 256, 0, stream>>>(cnt, dinv, cursor, N);
  k_scan1  <<<nb1, 1024, 0, stream>>>(cnt, N, rs, bsum);
  k_scan2  <<<1, 128, 0, stream>>>(bsum, nb1);
  k_scan3  <<<(N + 255) / 256, 256, 0, stream>>>(rs, bsum, N, E);
  k_fill   <<<(E + 255) / 256, 256, 0, stream>>>(src, dst, E, rs, cursor, dinv, epk);

  // ---- GCN layers ----
  int gb = (N + 63) / 64;
  int ab = (N * 64 + 255) / 256;  // one wave per node

  unsigned short* Wt0 = Wt;
  unsigned short* Wt1 = Wt + 16384;
  unsigned short* Wt2 = Wt + 2 * 16384;
  unsigned short* Wtr = Wt + 3 * 16384;

  k_gemm_mfma<<<gb, 256, 0, stream>>>(xb, Wtr, br, R, N);       // residual
  k_gemm_mfma<<<gb, 256, 0, stream>>>(xb, Wt0, nullptr, A, N);
  k_agg<<<ab, 256, 0, stream>>>((const unsigned*)A, rs, epk, dinv, b0,
                                (const unsigned*)R, (unsigned*)Hb, nullptr, N);
  k_gemm_mfma<<<gb, 256, 0, stream>>>(Hb, Wt1, nullptr, A, N);
  k_agg<<<ab, 256, 0, stream>>>((const unsigned*)A, rs, epk, dinv, b1,
                                nullptr, (unsigned*)R, nullptr, N);
  k_gemm_mfma<<<gb, 256, 0, stream>>>(R, Wt2, nullptr, A, N);
  k_agg<<<ab, 256, 0, stream>>>((const unsigned*)A, rs, epk, dinv, b2,
                                nullptr, nullptr, (float2*)d_out, N);
}

// Round 6
// 595.198 us; speedup vs baseline: 12.7058x; 1.1508x over previous
//
#include <hip/hip_runtime.h>
#include <hip/hip_bf16.h>
#include <cstdint>

// ---------------------------------------------------------------------------
// 3-layer GCN on MI355X — bf16 feature pipeline, f32 accumulate.
//   prep: x->bf16, W*->bf16 transposed (Wt[n][k]); CSR build (count/scan/fill)
//   R  = bf16( xb @ Wr + br )                     (MFMA GEMM)
//   A0 = bf16( xb @ W0 );  H0 = bf16(relu(S A0 + b0) + R)
//   A1 = bf16( H0 @ W1 );  H1 = bf16(relu(S A1 + b1))
//   A2 = bf16( H1 @ W2 );  out_f32 = relu(S A2 + b2)
// S = D^-1/2 (A+I) D^-1/2 applied gather-style, no float atomics;
// self-loop handled analytically (dinv^2 * h[node]).
//
// R1: f32 GEMM spill fix. R2: agg MLP8. R3: packed int2 CSR. R4: lesson —
// predicate the unroll, don't branch on degree. R5: bf16 pipeline + MFMA
// GEMM + predicated MLP16 (agg became VALU-bound: 45% VALUBusy, 9 instr/edge).
// R6: 2 nodes/wave (32-lane halves, uint2/lane) -> every edge-loop
// instruction serves 2 edges; k_count returns slot (k_fill atomic-free);
// dinv folded into scan1; zero/xcvt/wprep fused.
// ---------------------------------------------------------------------------

#define WS_ALIGN(x) (((x) + 255) & ~(size_t)255)

typedef __bf16 bf16x8 __attribute__((ext_vector_type(8)));
typedef float  floatx4 __attribute__((ext_vector_type(4)));

static __device__ __forceinline__ float bf_lo(unsigned u) {
  return __builtin_bit_cast(float, u << 16);
}
static __device__ __forceinline__ float bf_hi(unsigned u) {
  return __builtin_bit_cast(float, u & 0xffff0000u);
}
// f32 -> bf16 round-to-nearest-even (finite inputs only)
static __device__ __forceinline__ unsigned short f2bs(float f) {
  unsigned u = __builtin_bit_cast(unsigned, f);
  return (unsigned short)((u + 0x7fffu + ((u >> 16) & 1u)) >> 16);
}
static __device__ __forceinline__ unsigned pack2(float a, float b) {
  return (unsigned)f2bs(a) | ((unsigned)f2bs(b) << 16);
}

// ---------------- fused prep: zero cnt | x->bf16 | W->Wt bf16 -------------
__global__ void k_prep(const float* __restrict__ x, unsigned* __restrict__ xb, int n4,
                       int* __restrict__ cnt, int n,
                       const float* __restrict__ W0, const float* __restrict__ W1,
                       const float* __restrict__ W2, const float* __restrict__ Wr,
                       unsigned short* __restrict__ Wt, int zb, int xbn) {
  int b = blockIdx.x;
  if (b < zb) {
    int i = b * 256 + threadIdx.x;
    if (i < n) cnt[i] = 0;
  } else if (b < zb + xbn) {
    int i = (b - zb) * 256 + threadIdx.x;
    if (i < n4) {
      float4 v = ((const float4*)x)[i];
      uint2 o;
      o.x = pack2(v.x, v.y);
      o.y = pack2(v.z, v.w);
      ((uint2*)xb)[i] = o;
    }
  } else {
    int wb = b - zb - xbn;            // 0..255
    int mat = wb >> 6, blk = wb & 63;
    const float* W = mat == 0 ? W0 : mat == 1 ? W1 : mat == 2 ? W2 : Wr;
    unsigned short* T = Wt + (size_t)mat * 16384;
    int i = blk * 256 + threadIdx.x;  // i = k*128 + nn, coalesced read
    int k = i >> 7, nn = i & 127;
    T[nn * 128 + k] = f2bs(W[i]);
  }
}

// count in-degree AND hand each edge its slot (old value of the atomic)
__global__ void k_count(const int* __restrict__ dst, int E,
                        int* __restrict__ cnt, int* __restrict__ pos) {
  int e = blockIdx.x * blockDim.x + threadIdx.x;
  if (e < E) pos[e] = atomicAdd(&cnt[dst[e]], 1);
}

// Block-wise exclusive scan (Hillis-Steele in LDS), 1024/block; also dinv.
__global__ __launch_bounds__(1024) void k_scan1(const int* __restrict__ cnt, int n,
                                                int* __restrict__ rs, int* __restrict__ bsum,
                                                float* __restrict__ dinv) {
  __shared__ int tmp[1024];
  int tid = threadIdx.x;
  int i = blockIdx.x * 1024 + tid;
  int v = (i < n) ? cnt[i] : 0;
  if (i < n) dinv[i] = rsqrtf((float)(v + 1));  // +1 = self-loop; always > 0
  tmp[tid] = v;
  __syncthreads();
  for (int off = 1; off < 1024; off <<= 1) {
    int t = (tid >= off) ? tmp[tid - off] : 0;
    __syncthreads();
    tmp[tid] += t;
    __syncthreads();
  }
  if (i < n) rs[i] = tmp[tid] - v;           // exclusive
  if (tid == 1023) bsum[blockIdx.x] = tmp[1023];
}

__global__ __launch_bounds__(128) void k_scan2(int* bsum, int nb) {
  __shared__ int tmp[128];
  int tid = threadIdx.x;
  int v = (tid < nb) ? bsum[tid] : 0;
  tmp[tid] = v;
  __syncthreads();
  for (int off = 1; off < 128; off <<= 1) {
    int t = (tid >= off) ? tmp[tid - off] : 0;
    __syncthreads();
    tmp[tid] += t;
    __syncthreads();
  }
  if (tid < nb) bsum[tid] = tmp[tid] - v;    // exclusive
}

__global__ void k_scan3(int* rs, const int* __restrict__ bsum, int n, int E) {
  int i = blockIdx.x * blockDim.x + threadIdx.x;
  if (i < n) rs[i] += bsum[i >> 10];
  if (i == 0) rs[n] = E;
}

// Atomic-free packed fill: one 8 B scattered store per edge {src, bits(w)}.
__global__ void k_fill(const int* __restrict__ src, const int* __restrict__ dst, int E,
                       const int* __restrict__ rs, const int* __restrict__ pos,
                       const float* __restrict__ dinv,
                       int2* __restrict__ epk) {
  int e = blockIdx.x * blockDim.x + threadIdx.x;
  if (e < E) {
    int s = src[e], d = dst[e];
    int idx = rs[d] + pos[e];
    int2 v;
    v.x = s;
    v.y = __float_as_int(dinv[s] * dinv[d]);
    epk[idx] = v;
  }
}

// ---------------- bf16 MFMA GEMM: Y[n,128] = bf16( Xb[n,128] @ W + bias ) ---
// Wt pre-transposed [n][k] bf16, staged in 32 KB LDS. Block = 256 thr =
// 4 waves; each wave computes a 16-row x 128-col strip with 32 MFMAs.
// Layouts (verified, learn_hip m89/m120): A[m=lane&15][k=quad*8+j],
// B[k=quad*8+j][n=lane&15], C/D col=lane&15 row=quad*4+reg.
__global__ __launch_bounds__(256, 2) void k_gemm_mfma(
    const unsigned short* __restrict__ Xb,
    const unsigned short* __restrict__ Wt,
    const float* __restrict__ bias,
    unsigned short* __restrict__ Y,
    int n) {
  __shared__ unsigned short sWt[128 * 128];
  {
    const uint4* s4 = (const uint4*)Wt;
    uint4* d4 = (uint4*)sWt;
    for (int i = threadIdx.x; i < 2048; i += 256) d4[i] = s4[i];
  }
  __syncthreads();

  const int lane = threadIdx.x & 63;
  const int wave = threadIdx.x >> 6;
  const int l15 = lane & 15;
  const int quad = lane >> 4;
  const int rbase = blockIdx.x * 64 + wave * 16;

  const bf16x8* sW8 = (const bf16x8*)sWt;
  bf16x8 b[8][4];
#pragma unroll
  for (int ct = 0; ct < 8; ct++)
#pragma unroll
    for (int kc = 0; kc < 4; kc++)
      b[ct][kc] = sW8[(ct * 16 + l15) * 16 + kc * 4 + quad];

  int row = rbase + l15;
  row = row < n ? row : n - 1;
  const bf16x8* X8 = (const bf16x8*)Xb;
  bf16x8 a[4];
#pragma unroll
  for (int kc = 0; kc < 4; kc++)
    a[kc] = X8[(size_t)row * 16 + kc * 4 + quad];

  floatx4 acc[8];
#pragma unroll
  for (int ct = 0; ct < 8; ct++) acc[ct] = (floatx4){0.f, 0.f, 0.f, 0.f};

#pragma unroll
  for (int kc = 0; kc < 4; kc++)
#pragma unroll
    for (int ct = 0; ct < 8; ct++)
      acc[ct] = __builtin_amdgcn_mfma_f32_16x16x32_bf16(a[kc], b[ct][kc], acc[ct], 0, 0, 0);

  const int orow = rbase + quad * 4;
#pragma unroll
  for (int ct = 0; ct < 8; ct++) {
    const int c = ct * 16 + l15;
    const float bv = bias ? bias[c] : 0.f;
#pragma unroll
    for (int r4 = 0; r4 < 4; r4++) {
      int r = orow + r4;
      if (r < n) Y[(size_t)r * 128 + c] = f2bs(acc[ct][r4] + bv);
    }
  }
}

// ---------------- aggregation ----------------
// TWO nodes per wave: 32-lane half-waves each own a node; lane covers 4 bf16
// cols as one uint2 (8 B). Every edge-loop instruction serves 2 edges, and
// each of the 16 in-flight dwordx2 gathers covers 2 edges (effective MLP 32).
// Predicated MLP-16: invalid slots clamp to end-1 (dup gather = L1 hit),
// weight 0 — pipeline depth never degrades with degree (R4 lesson).
__global__ __launch_bounds__(256) void k_agg(
    const uint2* __restrict__ H,         // bf16x4 per lane [n*32]
    const int* __restrict__ rs,
    const int2* __restrict__ epk,
    const float* __restrict__ dinv,
    const float* __restrict__ bias,
    const uint2* __restrict__ resid,     // bf16x4 or null
    uint2* __restrict__ outb,            // bf16 out (layers 0,1) or null
    float4* __restrict__ outf,           // f32 out (layer 2) or null
    int n) {
  int node = blockIdx.x * 8 + (threadIdx.x >> 5);
  int l = threadIdx.x & 31;
  if (node >= n) return;

  float di = dinv[node];
  float ws = di * di;
  uint2 hv = H[(size_t)node * 32 + l];
  float a0 = bf_lo(hv.x) * ws, a1 = bf_hi(hv.x) * ws;
  float a2 = bf_lo(hv.y) * ws, a3 = bf_hi(hv.y) * ws;

  int beg = rs[node], end = rs[node + 1];
  for (int j0 = beg; j0 < end; j0 += 16) {
    int si[16];
    float w[16];
#pragma unroll
    for (int u = 0; u < 16; u++) {
      int jj = j0 + u;
      int2 ee = epk[jj < end ? jj : end - 1];
      si[u] = ee.x;
      w[u] = (jj < end) ? __int_as_float(ee.y) : 0.f;
    }
    uint2 h[16];
#pragma unroll
    for (int u = 0; u < 16; u++) h[u] = H[(size_t)(unsigned)si[u] * 32 + l];
#pragma unroll
    for (int u = 0; u < 16; u++) {
      a0 = fmaf(w[u], bf_lo(h[u].x), a0);
      a1 = fmaf(w[u], bf_hi(h[u].x), a1);
      a2 = fmaf(w[u], bf_lo(h[u].y), a2);
      a3 = fmaf(w[u], bf_hi(h[u].y), a3);
    }
  }

  float4 b4 = ((const float4*)bias)[l];
  a0 = fmaxf(a0 + b4.x, 0.f);
  a1 = fmaxf(a1 + b4.y, 0.f);
  a2 = fmaxf(a2 + b4.z, 0.f);
  a3 = fmaxf(a3 + b4.w, 0.f);
  if (resid) {
    uint2 r = resid[(size_t)node * 32 + l];
    a0 += bf_lo(r.x);
    a1 += bf_hi(r.x);
    a2 += bf_lo(r.y);
    a3 += bf_hi(r.y);
  }
  if (outb) {
    uint2 o;
    o.x = pack2(a0, a1);
    o.y = pack2(a2, a3);
    outb[(size_t)node * 32 + l] = o;
  } else {
    float4 o;
    o.x = a0; o.y = a1; o.z = a2; o.w = a3;
    outf[(size_t)node * 32 + l] = o;
  }
}

extern "C" void kernel_launch(void* const* d_in, const int* in_sizes, int n_in,
                              void* d_out, int out_size, void* d_ws, size_t ws_size,
                              hipStream_t stream) {
  const float* x  = (const float*)d_in[0];
  const int* edges = (const int*)d_in[1];
  const float* W0 = (const float*)d_in[2];
  const float* b0 = (const float*)d_in[3];
  const float* W1 = (const float*)d_in[4];
  const float* b1 = (const float*)d_in[5];
  const float* W2 = (const float*)d_in[6];
  const float* b2 = (const float*)d_in[7];
  const float* Wr = (const float*)d_in[8];
  const float* br = (const float*)d_in[9];

  int N = in_sizes[0] / 128;
  int E = in_sizes[1] / 2;
  const int* src = edges;
  const int* dst = edges + E;

  char* ws = (char*)d_ws;
  size_t off = 0;
  auto alloc = [&](size_t bytes) -> void* {
    void* p = ws + off; off = WS_ALIGN(off + bytes); return p;
  };
  int*   cnt    = (int*)  alloc((size_t)N * 4);
  float* dinv   = (float*)alloc((size_t)N * 4);
  int*   rs     = (int*)  alloc((size_t)(N + 1) * 4);
  int*   bsum   = (int*)  alloc(1024);
  int*   pos    = (int*)  alloc((size_t)E * 4);
  int2*  epk    = (int2*) alloc((size_t)E * 8);
  unsigned short* xb = (unsigned short*)alloc((size_t)N * 128 * 2);
  unsigned short* Wt = (unsigned short*)alloc((size_t)4 * 16384 * 2);
  unsigned short* A  = (unsigned short*)alloc((size_t)N * 128 * 2);
  unsigned short* Hb = (unsigned short*)alloc((size_t)N * 128 * 2);
  unsigned short* R  = (unsigned short*)alloc((size_t)N * 128 * 2);
  (void)ws_size; (void)n_in; (void)out_size;

  int nb1 = (N + 1023) / 1024;   // 98 for N=100000 (must be <= 128)

  // ---- fused prep + CSR build ----
  int n4 = N * 128 / 4;
  int zb = (N + 255) / 256;
  int xbn = (n4 + 255) / 256;
  k_prep <<<zb + xbn + 256, 256, 0, stream>>>(x, (unsigned*)xb, n4, cnt, N,
                                              W0, W1, W2, Wr, Wt, zb, xbn);
  k_count<<<(E + 255) / 256, 256, 0, stream>>>(dst, E, cnt, pos);
  k_scan1<<<nb1, 1024, 0, stream>>>(cnt, N, rs, bsum, dinv);
  k_scan2<<<1, 128, 0, stream>>>(bsum, nb1);
  k_scan3<<<(N + 255) / 256, 256, 0, stream>>>(rs, bsum, N, E);
  k_fill <<<(E + 255) / 256, 256, 0, stream>>>(src, dst, E, rs, pos, dinv, epk);

  // ---- GCN layers ----
  int gb = (N + 63) / 64;
  int ab = (N + 7) / 8;   // 8 nodes (half-waves) per 256-thread block

  unsigned short* Wt0 = Wt;
  unsigned short* Wt1 = Wt + 16384;
  unsigned short* Wt2 = Wt + 2 * 16384;
  unsigned short* Wtr = Wt + 3 * 16384;

  k_gemm_mfma<<<gb, 256, 0, stream>>>(xb, Wtr, br, R, N);       // residual
  k_gemm_mfma<<<gb, 256, 0, stream>>>(xb, Wt0, nullptr, A, N);
  k_agg<<<ab, 256, 0, stream>>>((const uint2*)A, rs, epk, dinv, b0,
                                (const uint2*)R, (uint2*)Hb, nullptr, N);
  k_gemm_mfma<<<gb, 256, 0, stream>>>(Hb, Wt1, nullptr, A, N);
  k_agg<<<ab, 256, 0, stream>>>((const uint2*)A, rs, epk, dinv, b1,
                                nullptr, (uint2*)R, nullptr, N);
  k_gemm_mfma<<<gb, 256, 0, stream>>>(R, Wt2, nullptr, A, N);
  k_agg<<<ab, 256, 0, stream>>>((const uint2*)A, rs, epk, dinv, b2,
                                nullptr, nullptr, (float4*)d_out, N);
}

// Round 7
// 592.676 us; speedup vs baseline: 12.7598x; 1.0043x over previous
//
#include <hip/hip_runtime.h>
#include <hip/hip_bf16.h>
#include <cstdint>

// ---------------------------------------------------------------------------
// 3-layer GCN on MI355X — bf16 feature pipeline, f32 accumulate.
//   prep: x->bf16, W*->bf16 transposed (Wt[n][k]); CSR build (count/scan/fill)
//   R  = bf16( xb @ Wr + br )                     (MFMA GEMM)
//   A0 = bf16( xb @ W0 );  H0 = bf16(relu(S A0 + b0) + R)
//   A1 = bf16( H0 @ W1 );  H1 = bf16(relu(S A1 + b1))
//   A2 = bf16( H1 @ W2 );  out_f32 = relu(S A2 + b2)
// S = D^-1/2 (A+I) D^-1/2 applied gather-style, no float atomics;
// self-loop handled analytically (dinv^2 * h[node]).
//
// R1: f32 GEMM spill fix. R2: agg MLP8. R3: packed int2 CSR. R4: predicate
// the unroll, don't branch on degree. R5: bf16 + MFMA GEMM + MLP16.
// R6: 2 nodes/wave; atomic-free fill. R7 (this): k_agg VGPR_Count was 36 —
// compiler re-serialized the MLP-16 into ~4-wide batches to minimize
// registers. __launch_bounds__(256,4) grants ~128 VGPR so the 16 gathers
// actually stay in flight. scan3 eliminated (fill/agg add bsum on the fly).
// ---------------------------------------------------------------------------

#define WS_ALIGN(x) (((x) + 255) & ~(size_t)255)

typedef __bf16 bf16x8 __attribute__((ext_vector_type(8)));
typedef float  floatx4 __attribute__((ext_vector_type(4)));

static __device__ __forceinline__ float bf_lo(unsigned u) {
  return __builtin_bit_cast(float, u << 16);
}
static __device__ __forceinline__ float bf_hi(unsigned u) {
  return __builtin_bit_cast(float, u & 0xffff0000u);
}
// f32 -> bf16 round-to-nearest-even (finite inputs only)
static __device__ __forceinline__ unsigned short f2bs(float f) {
  unsigned u = __builtin_bit_cast(unsigned, f);
  return (unsigned short)((u + 0x7fffu + ((u >> 16) & 1u)) >> 16);
}
static __device__ __forceinline__ unsigned pack2(float a, float b) {
  return (unsigned)f2bs(a) | ((unsigned)f2bs(b) << 16);
}

// ---------------- fused prep: zero cnt | x->bf16 | W->Wt bf16 -------------
__global__ void k_prep(const float* __restrict__ x, unsigned* __restrict__ xb, int n4,
                       int* __restrict__ cnt, int n,
                       const float* __restrict__ W0, const float* __restrict__ W1,
                       const float* __restrict__ W2, const float* __restrict__ Wr,
                       unsigned short* __restrict__ Wt, int zb, int xbn) {
  int b = blockIdx.x;
  if (b < zb) {
    int i = b * 256 + threadIdx.x;
    if (i < n) cnt[i] = 0;
  } else if (b < zb + xbn) {
    int i = (b - zb) * 256 + threadIdx.x;
    if (i < n4) {
      float4 v = ((const float4*)x)[i];
      uint2 o;
      o.x = pack2(v.x, v.y);
      o.y = pack2(v.z, v.w);
      ((uint2*)xb)[i] = o;
    }
  } else {
    int wb = b - zb - xbn;            // 0..255
    int mat = wb >> 6, blk = wb & 63;
    const float* W = mat == 0 ? W0 : mat == 1 ? W1 : mat == 2 ? W2 : Wr;
    unsigned short* T = Wt + (size_t)mat * 16384;
    int i = blk * 256 + threadIdx.x;  // i = k*128 + nn, coalesced read
    int k = i >> 7, nn = i & 127;
    T[nn * 128 + k] = f2bs(W[i]);
  }
}

// count in-degree AND hand each edge its slot (old value of the atomic)
__global__ void k_count(const int* __restrict__ dst, int E,
                        int* __restrict__ cnt, int* __restrict__ pos) {
  int e = blockIdx.x * blockDim.x + threadIdx.x;
  if (e < E) pos[e] = atomicAdd(&cnt[dst[e]], 1);
}

// Block-wise exclusive scan (Hillis-Steele in LDS), 1024/block; also dinv.
__global__ __launch_bounds__(1024) void k_scan1(const int* __restrict__ cnt, int n,
                                                int* __restrict__ rs, int* __restrict__ bsum,
                                                float* __restrict__ dinv) {
  __shared__ int tmp[1024];
  int tid = threadIdx.x;
  int i = blockIdx.x * 1024 + tid;
  int v = (i < n) ? cnt[i] : 0;
  if (i < n) dinv[i] = rsqrtf((float)(v + 1));  // +1 = self-loop; always > 0
  tmp[tid] = v;
  __syncthreads();
  for (int off = 1; off < 1024; off <<= 1) {
    int t = (tid >= off) ? tmp[tid - off] : 0;
    __syncthreads();
    tmp[tid] += t;
    __syncthreads();
  }
  if (i < n) rs[i] = tmp[tid] - v;           // exclusive (block-local)
  if (tid == 1023) bsum[blockIdx.x] = tmp[1023];
}

__global__ __launch_bounds__(128) void k_scan2(int* bsum, int nb) {
  __shared__ int tmp[128];
  int tid = threadIdx.x;
  int v = (tid < nb) ? bsum[tid] : 0;
  tmp[tid] = v;
  __syncthreads();
  for (int off = 1; off < 128; off <<= 1) {
    int t = (tid >= off) ? tmp[tid - off] : 0;
    __syncthreads();
    tmp[tid] += t;
    __syncthreads();
  }
  if (tid < nb) bsum[tid] = tmp[tid] - v;    // exclusive
}

// Atomic-free packed fill: one 8 B scattered store per edge {src, bits(w)}.
// Final CSR offset computed on the fly: rs[d] + bsum[d>>10] + pos[e].
__global__ void k_fill(const int* __restrict__ src, const int* __restrict__ dst, int E,
                       const int* __restrict__ rs, const int* __restrict__ bsum,
                       const int* __restrict__ pos,
                       const float* __restrict__ dinv,
                       int2* __restrict__ epk) {
  int e = blockIdx.x * blockDim.x + threadIdx.x;
  if (e < E) {
    int s = src[e], d = dst[e];
    int idx = rs[d] + bsum[d >> 10] + pos[e];
    int2 v;
    v.x = s;
    v.y = __float_as_int(dinv[s] * dinv[d]);
    epk[idx] = v;
  }
}

// ---------------- bf16 MFMA GEMM: Y[n,128] = bf16( Xb[n,128] @ W + bias ) ---
// Wt pre-transposed [n][k] bf16, staged in 32 KB LDS. Block = 256 thr =
// 4 waves; each wave computes a 16-row x 128-col strip with 32 MFMAs.
// Layouts (verified, learn_hip m89/m120): A[m=lane&15][k=quad*8+j],
// B[k=quad*8+j][n=lane&15], C/D col=lane&15 row=quad*4+reg.
__global__ __launch_bounds__(256, 2) void k_gemm_mfma(
    const unsigned short* __restrict__ Xb,
    const unsigned short* __restrict__ Wt,
    const float* __restrict__ bias,
    unsigned short* __restrict__ Y,
    int n) {
  __shared__ unsigned short sWt[128 * 128];
  {
    const uint4* s4 = (const uint4*)Wt;
    uint4* d4 = (uint4*)sWt;
    for (int i = threadIdx.x; i < 2048; i += 256) d4[i] = s4[i];
  }
  __syncthreads();

  const int lane = threadIdx.x & 63;
  const int wave = threadIdx.x >> 6;
  const int l15 = lane & 15;
  const int quad = lane >> 4;
  const int rbase = blockIdx.x * 64 + wave * 16;

  const bf16x8* sW8 = (const bf16x8*)sWt;
  bf16x8 b[8][4];
#pragma unroll
  for (int ct = 0; ct < 8; ct++)
#pragma unroll
    for (int kc = 0; kc < 4; kc++)
      b[ct][kc] = sW8[(ct * 16 + l15) * 16 + kc * 4 + quad];

  int row = rbase + l15;
  row = row < n ? row : n - 1;
  const bf16x8* X8 = (const bf16x8*)Xb;
  bf16x8 a[4];
#pragma unroll
  for (int kc = 0; kc < 4; kc++)
    a[kc] = X8[(size_t)row * 16 + kc * 4 + quad];

  floatx4 acc[8];
#pragma unroll
  for (int ct = 0; ct < 8; ct++) acc[ct] = (floatx4){0.f, 0.f, 0.f, 0.f};

#pragma unroll
  for (int kc = 0; kc < 4; kc++)
#pragma unroll
    for (int ct = 0; ct < 8; ct++)
      acc[ct] = __builtin_amdgcn_mfma_f32_16x16x32_bf16(a[kc], b[ct][kc], acc[ct], 0, 0, 0);

  const int orow = rbase + quad * 4;
#pragma unroll
  for (int ct = 0; ct < 8; ct++) {
    const int c = ct * 16 + l15;
    const float bv = bias ? bias[c] : 0.f;
#pragma unroll
    for (int r4 = 0; r4 < 4; r4++) {
      int r = orow + r4;
      if (r < n) Y[(size_t)r * 128 + c] = f2bs(acc[ct][r4] + bv);
    }
  }
}

// ---------------- aggregation ----------------
// TWO nodes per wave: 32-lane half-waves each own a node; lane covers 4 bf16
// cols as one uint2 (8 B). Predicated MLP-16 (R4 lesson). launch_bounds
// (256,4) grants ~128 VGPR so the compiler keeps all 16 gathers in flight
// (R6's default schedule collapsed to VGPR=36 => ~4-wide batches).
__global__ __launch_bounds__(256, 4) void k_agg(
    const uint2* __restrict__ H,         // bf16x4 per lane [n*32]
    const int* __restrict__ rs,
    const int* __restrict__ bsum,
    const int2* __restrict__ epk,
    const float* __restrict__ dinv,
    const float* __restrict__ bias,
    const uint2* __restrict__ resid,     // bf16x4 or null
    uint2* __restrict__ outb,            // bf16 out (layers 0,1) or null
    float4* __restrict__ outf,           // f32 out (layer 2) or null
    int n, int E) {
  int node = blockIdx.x * 8 + (threadIdx.x >> 5);
  int l = threadIdx.x & 31;
  if (node >= n) return;

  float di = dinv[node];
  float ws = di * di;
  uint2 hv = H[(size_t)node * 32 + l];
  float a0 = bf_lo(hv.x) * ws, a1 = bf_hi(hv.x) * ws;
  float a2 = bf_lo(hv.y) * ws, a3 = bf_hi(hv.y) * ws;

  int beg = rs[node] + bsum[node >> 10];
  int end = (node == n - 1) ? E : rs[node + 1] + bsum[(node + 1) >> 10];

  for (int j0 = beg; j0 < end; j0 += 16) {
    int si[16];
    float w[16];
#pragma unroll
    for (int u = 0; u < 16; u++) {
      int jj = j0 + u;
      int2 ee = epk[jj < end ? jj : end - 1];
      si[u] = ee.x;
      w[u] = (jj < end) ? __int_as_float(ee.y) : 0.f;
    }
    uint2 h[16];
#pragma unroll
    for (int u = 0; u < 16; u++) h[u] = H[(size_t)(unsigned)si[u] * 32 + l];
#pragma unroll
    for (int u = 0; u < 16; u++) {
      a0 = fmaf(w[u], bf_lo(h[u].x), a0);
      a1 = fmaf(w[u], bf_hi(h[u].x), a1);
      a2 = fmaf(w[u], bf_lo(h[u].y), a2);
      a3 = fmaf(w[u], bf_hi(h[u].y), a3);
    }
  }

  float4 b4 = ((const float4*)bias)[l];
  a0 = fmaxf(a0 + b4.x, 0.f);
  a1 = fmaxf(a1 + b4.y, 0.f);
  a2 = fmaxf(a2 + b4.z, 0.f);
  a3 = fmaxf(a3 + b4.w, 0.f);
  if (resid) {
    uint2 r = resid[(size_t)node * 32 + l];
    a0 += bf_lo(r.x);
    a1 += bf_hi(r.x);
    a2 += bf_lo(r.y);
    a3 += bf_hi(r.y);
  }
  if (outb) {
    uint2 o;
    o.x = pack2(a0, a1);
    o.y = pack2(a2, a3);
    outb[(size_t)node * 32 + l] = o;
  } else {
    float4 o;
    o.x = a0; o.y = a1; o.z = a2; o.w = a3;
    outf[(size_t)node * 32 + l] = o;
  }
}

extern "C" void kernel_launch(void* const* d_in, const int* in_sizes, int n_in,
                              void* d_out, int out_size, void* d_ws, size_t ws_size,
                              hipStream_t stream) {
  const float* x  = (const float*)d_in[0];
  const int* edges = (const int*)d_in[1];
  const float* W0 = (const float*)d_in[2];
  const float* b0 = (const float*)d_in[3];
  const float* W1 = (const float*)d_in[4];
  const float* b1 = (const float*)d_in[5];
  const float* W2 = (const float*)d_in[6];
  const float* b2 = (const float*)d_in[7];
  const float* Wr = (const float*)d_in[8];
  const float* br = (const float*)d_in[9];

  int N = in_sizes[0] / 128;
  int E = in_sizes[1] / 2;
  const int* src = edges;
  const int* dst = edges + E;

  char* ws = (char*)d_ws;
  size_t off = 0;
  auto alloc = [&](size_t bytes) -> void* {
    void* p = ws + off; off = WS_ALIGN(off + bytes); return p;
  };
  int*   cnt    = (int*)  alloc((size_t)N * 4);
  float* dinv   = (float*)alloc((size_t)N * 4);
  int*   rs     = (int*)  alloc((size_t)(N + 1) * 4);
  int*   bsum   = (int*)  alloc(1024);
  int*   pos    = (int*)  alloc((size_t)E * 4);
  int2*  epk    = (int2*) alloc((size_t)E * 8);
  unsigned short* xb = (unsigned short*)alloc((size_t)N * 128 * 2);
  unsigned short* Wt = (unsigned short*)alloc((size_t)4 * 16384 * 2);
  unsigned short* A  = (unsigned short*)alloc((size_t)N * 128 * 2);
  unsigned short* Hb = (unsigned short*)alloc((size_t)N * 128 * 2);
  unsigned short* R  = (unsigned short*)alloc((size_t)N * 128 * 2);
  (void)ws_size; (void)n_in; (void)out_size;

  int nb1 = (N + 1023) / 1024;   // 98 for N=100000 (must be <= 128)

  // ---- fused prep + CSR build ----
  int n4 = N * 128 / 4;
  int zb = (N + 255) / 256;
  int xbn = (n4 + 255) / 256;
  k_prep <<<zb + xbn + 256, 256, 0, stream>>>(x, (unsigned*)xb, n4, cnt, N,
                                              W0, W1, W2, Wr, Wt, zb, xbn);
  k_count<<<(E + 255) / 256, 256, 0, stream>>>(dst, E, cnt, pos);
  k_scan1<<<nb1, 1024, 0, stream>>>(cnt, N, rs, bsum, dinv);
  k_scan2<<<1, 128, 0, stream>>>(bsum, nb1);
  k_fill <<<(E + 255) / 256, 256, 0, stream>>>(src, dst, E, rs, bsum, pos, dinv, epk);

  // ---- GCN layers ----
  int gb = (N + 63) / 64;
  int ab = (N + 7) / 8;   // 8 nodes (half-waves) per 256-thread block

  unsigned short* Wt0 = Wt;
  unsigned short* Wt1 = Wt + 16384;
  unsigned short* Wt2 = Wt + 2 * 16384;
  unsigned short* Wtr = Wt + 3 * 16384;

  k_gemm_mfma<<<gb, 256, 0, stream>>>(xb, Wtr, br, R, N);       // residual
  k_gemm_mfma<<<gb, 256, 0, stream>>>(xb, Wt0, nullptr, A, N);
  k_agg<<<ab, 256, 0, stream>>>((const uint2*)A, rs, bsum, epk, dinv, b0,
                                (const uint2*)R, (uint2*)Hb, nullptr, N, E);
  k_gemm_mfma<<<gb, 256, 0, stream>>>(Hb, Wt1, nullptr, A, N);
  k_agg<<<ab, 256, 0, stream>>>((const uint2*)A, rs, bsum, epk, dinv, b1,
                                nullptr, (uint2*)R, nullptr, N, E);
  k_gemm_mfma<<<gb, 256, 0, stream>>>(R, Wt2, nullptr, A, N);
  k_agg<<<ab, 256, 0, stream>>>((const uint2*)A, rs, bsum, epk, dinv, b2,
                                nullptr, nullptr, (float4*)d_out, N, E);
}

// Round 9
// 527.202 us; speedup vs baseline: 14.3445x; 1.1242x over previous
//
#include <hip/hip_runtime.h>
#include <hip/hip_bf16.h>
#include <cstdint>

// ---------------------------------------------------------------------------
// 3-layer GCN on MI355X — bf16 feature pipeline, f32 accumulate.
//   prep: x->bf16, W*->bf16 transposed (Wt[n][k]); CSR build (count/scan/fill)
//   R  = bf16( xb @ Wr + br )                     (MFMA GEMM)
//   A0 = bf16( xb @ W0 );  H0 = bf16(relu(S A0 + b0) + R)
//   A1 = bf16( H0 @ W1 );  H1 = bf16(relu(S A1 + b1))
//   A2 = bf16( H1 @ W2 );  out_f32 = relu(S A2 + b2)
// S = D^-1/2 (A+I) D^-1/2 gather-style, no float atomics; self-loop
// analytic (dinv^2 * h[node]).
//
// R1: GEMM spill fix. R2: MLP8. R3: packed int2 CSR. R4: predicate unroll.
// R5: bf16 + MFMA. R6: 2 nodes/wave. R7: launch_bounds can't force deep
// gather pipelining. R8: 4 nodes/wave + 8-padded CSR (no predication, int4
// epk reads) — COMPILE FAILED: macro param `w` got substituted into `(h).w`
// member access. R9 (this): identical plan, FMA8 macro -> inline function.
// ---------------------------------------------------------------------------

#define WS_ALIGN(x) (((x) + 255) & ~(size_t)255)

typedef __bf16 bf16x8 __attribute__((ext_vector_type(8)));
typedef float  floatx4 __attribute__((ext_vector_type(4)));

static __device__ __forceinline__ float bf_lo(unsigned u) {
  return __builtin_bit_cast(float, u << 16);
}
static __device__ __forceinline__ float bf_hi(unsigned u) {
  return __builtin_bit_cast(float, u & 0xffff0000u);
}
// f32 -> bf16 round-to-nearest-even (finite inputs only)
static __device__ __forceinline__ unsigned short f2bs(float f) {
  unsigned u = __builtin_bit_cast(unsigned, f);
  return (unsigned short)((u + 0x7fffu + ((u >> 16) & 1u)) >> 16);
}
static __device__ __forceinline__ unsigned pack2(float a, float b) {
  return (unsigned)f2bs(a) | ((unsigned)f2bs(b) << 16);
}

// ---------------- fused prep: zero cnt | x->bf16 | W->Wt bf16 -------------
__global__ void k_prep(const float* __restrict__ x, unsigned* __restrict__ xb, int n4,
                       int* __restrict__ cnt, int n,
                       const float* __restrict__ W0, const float* __restrict__ W1,
                       const float* __restrict__ W2, const float* __restrict__ Wr,
                       unsigned short* __restrict__ Wt, int zb, int xbn) {
  int b = blockIdx.x;
  if (b < zb) {
    int i = b * 256 + threadIdx.x;
    if (i < n) cnt[i] = 0;
  } else if (b < zb + xbn) {
    int i = (b - zb) * 256 + threadIdx.x;
    if (i < n4) {
      float4 v = ((const float4*)x)[i];
      uint2 o;
      o.x = pack2(v.x, v.y);
      o.y = pack2(v.z, v.w);
      ((uint2*)xb)[i] = o;
    }
  } else {
    int wb = b - zb - xbn;            // 0..255
    int mat = wb >> 6, blk = wb & 63;
    const float* W = mat == 0 ? W0 : mat == 1 ? W1 : mat == 2 ? W2 : Wr;
    unsigned short* T = Wt + (size_t)mat * 16384;
    int i = blk * 256 + threadIdx.x;  // i = k*128 + nn, coalesced read
    int k = i >> 7, nn = i & 127;
    T[nn * 128 + k] = f2bs(W[i]);
  }
}

// count in-degree AND hand each edge its slot (old value of the atomic)
__global__ void k_count(const int* __restrict__ dst, int E,
                        int* __restrict__ cnt, int* __restrict__ pos) {
  int e = blockIdx.x * blockDim.x + threadIdx.x;
  if (e < E) pos[e] = atomicAdd(&cnt[dst[e]], 1);
}

// Block-wise exclusive scan over PADDED counts ((cnt+7)&~7), 1024/block.
// Also computes dinv from the true count.
__global__ __launch_bounds__(1024) void k_scan1(const int* __restrict__ cnt, int n,
                                                int* __restrict__ rs, int* __restrict__ bsum,
                                                float* __restrict__ dinv) {
  __shared__ int tmp[1024];
  int tid = threadIdx.x;
  int i = blockIdx.x * 1024 + tid;
  int v = (i < n) ? cnt[i] : 0;
  if (i < n) dinv[i] = rsqrtf((float)(v + 1));  // +1 = self-loop; always > 0
  int vp = (v + 7) & ~7;                        // 8-padded segment size
  tmp[tid] = vp;
  __syncthreads();
  for (int off = 1; off < 1024; off <<= 1) {
    int t = (tid >= off) ? tmp[tid - off] : 0;
    __syncthreads();
    tmp[tid] += t;
    __syncthreads();
  }
  if (i < n) rs[i] = tmp[tid] - vp;          // exclusive (block-local, padded)
  if (tid == 1023) bsum[blockIdx.x] = tmp[1023];
}

__global__ __launch_bounds__(128) void k_scan2(int* bsum, int nb) {
  __shared__ int tmp[128];
  int tid = threadIdx.x;
  int v = (tid < nb) ? bsum[tid] : 0;
  tmp[tid] = v;
  __syncthreads();
  for (int off = 1; off < 128; off <<= 1) {
    int t = (tid >= off) ? tmp[tid - off] : 0;
    __syncthreads();
    tmp[tid] += t;
    __syncthreads();
  }
  if (tid < nb) bsum[tid] = tmp[tid] - v;    // exclusive
}

// Atomic-free packed fill + pad writer. Threads [0,E): scatter one 8 B store
// per edge {src, bits(w)} to slot rs[d]+bsum+pos. Threads [E, E+n): node
// pad slots [cnt, (cnt+7)&~7) get {0,0} (gather of node 0 with weight 0).
__global__ void k_fill(const int* __restrict__ src, const int* __restrict__ dst, int E,
                       const int* __restrict__ rs, const int* __restrict__ bsum,
                       const int* __restrict__ pos, const int* __restrict__ cnt,
                       const float* __restrict__ dinv,
                       int2* __restrict__ epk, int n) {
  int e = blockIdx.x * blockDim.x + threadIdx.x;
  if (e < E) {
    int s = src[e], d = dst[e];
    int idx = rs[d] + bsum[d >> 10] + pos[e];
    int2 v;
    v.x = s;
    v.y = __float_as_int(dinv[s] * dinv[d]);
    epk[idx] = v;
  } else if (e - E < n) {
    int node = e - E;
    int c = cnt[node];
    int cp = (c + 7) & ~7;
    int base = rs[node] + bsum[node >> 10];
    int2 z; z.x = 0; z.y = 0;
    for (int k = base + c; k < base + cp; k++) epk[k] = z;
  }
}

// ---------------- bf16 MFMA GEMM: Y[n,128] = bf16( Xb[n,128] @ W + bias ) ---
// Wt pre-transposed [n][k] bf16, staged in 32 KB LDS. Block = 256 thr =
// 4 waves; each wave computes a 16-row x 128-col strip with 32 MFMAs.
// Layouts (verified, learn_hip m89/m120): A[m=lane&15][k=quad*8+j],
// B[k=quad*8+j][n=lane&15], C/D col=lane&15 row=quad*4+reg.
__global__ __launch_bounds__(256, 2) void k_gemm_mfma(
    const unsigned short* __restrict__ Xb,
    const unsigned short* __restrict__ Wt,
    const float* __restrict__ bias,
    unsigned short* __restrict__ Y,
    int n) {
  __shared__ unsigned short sWt[128 * 128];
  {
    const uint4* s4 = (const uint4*)Wt;
    uint4* d4 = (uint4*)sWt;
    for (int i = threadIdx.x; i < 2048; i += 256) d4[i] = s4[i];
  }
  __syncthreads();

  const int lane = threadIdx.x & 63;
  const int wave = threadIdx.x >> 6;
  const int l15 = lane & 15;
  const int quad = lane >> 4;
  const int rbase = blockIdx.x * 64 + wave * 16;

  const bf16x8* sW8 = (const bf16x8*)sWt;
  bf16x8 b[8][4];
#pragma unroll
  for (int ct = 0; ct < 8; ct++)
#pragma unroll
    for (int kc = 0; kc < 4; kc++)
      b[ct][kc] = sW8[(ct * 16 + l15) * 16 + kc * 4 + quad];

  int row = rbase + l15;
  row = row < n ? row : n - 1;
  const bf16x8* X8 = (const bf16x8*)Xb;
  bf16x8 a[4];
#pragma unroll
  for (int kc = 0; kc < 4; kc++)
    a[kc] = X8[(size_t)row * 16 + kc * 4 + quad];

  floatx4 acc[8];
#pragma unroll
  for (int ct = 0; ct < 8; ct++) acc[ct] = (floatx4){0.f, 0.f, 0.f, 0.f};

#pragma unroll
  for (int kc = 0; kc < 4; kc++)
#pragma unroll
    for (int ct = 0; ct < 8; ct++)
      acc[ct] = __builtin_amdgcn_mfma_f32_16x16x32_bf16(a[kc], b[ct][kc], acc[ct], 0, 0, 0);

  const int orow = rbase + quad * 4;
#pragma unroll
  for (int ct = 0; ct < 8; ct++) {
    const int c = ct * 16 + l15;
    const float bv = bias ? bias[c] : 0.f;
#pragma unroll
    for (int r4 = 0; r4 < 4; r4++) {
      int r = orow + r4;
      if (r < n) Y[(size_t)r * 128 + c] = f2bs(acc[ct][r4] + bv);
    }
  }
}

// ---------------- aggregation ----------------
// FOUR nodes per wave: 16-lane quarter-waves each own a node; lane covers
// 8 bf16 cols as one uint4 (16 B). One gather instruction = 4 edges.
// CSR segments are 8-padded, so the MLP-8 batch needs NO predication and
// epk reads are 4x int4 (16 B aligned, quarter-uniform broadcast).
static __device__ __forceinline__ void fma8(float wgt, uint4 h, float* a) {
  a[0] = fmaf(wgt, bf_lo(h.x), a[0]);
  a[1] = fmaf(wgt, bf_hi(h.x), a[1]);
  a[2] = fmaf(wgt, bf_lo(h.y), a[2]);
  a[3] = fmaf(wgt, bf_hi(h.y), a[3]);
  a[4] = fmaf(wgt, bf_lo(h.z), a[4]);
  a[5] = fmaf(wgt, bf_hi(h.z), a[5]);
  a[6] = fmaf(wgt, bf_lo(h.w), a[6]);
  a[7] = fmaf(wgt, bf_hi(h.w), a[7]);
}

__global__ __launch_bounds__(256, 4) void k_agg(
    const uint4* __restrict__ H,         // bf16x8 per lane [n*16]
    const int* __restrict__ rs,
    const int* __restrict__ bsum,
    const int* __restrict__ cnt,
    const int2* __restrict__ epk,
    const float* __restrict__ dinv,
    const float* __restrict__ bias,
    const uint4* __restrict__ resid,     // bf16x8 or null
    uint4* __restrict__ outb,            // bf16 out (layers 0,1) or null
    float4* __restrict__ outf,           // f32 out (layer 2) or null
    int n) {
  int node = blockIdx.x * 16 + (threadIdx.x >> 4);
  int l = threadIdx.x & 15;
  if (node >= n) return;

  float di = dinv[node];
  float ws = di * di;
  uint4 hv = H[(size_t)node * 16 + l];
  float a[8];
  a[0] = bf_lo(hv.x) * ws; a[1] = bf_hi(hv.x) * ws;
  a[2] = bf_lo(hv.y) * ws; a[3] = bf_hi(hv.y) * ws;
  a[4] = bf_lo(hv.z) * ws; a[5] = bf_hi(hv.z) * ws;
  a[6] = bf_lo(hv.w) * ws; a[7] = bf_hi(hv.w) * ws;

  int beg = rs[node] + bsum[node >> 10];
  int pdeg = (cnt[node] + 7) & ~7;     // 8-padded degree
  const int4* epk4 = (const int4*)epk;

  for (int j = 0; j < pdeg; j += 8) {
    int b2 = (beg + j) >> 1;           // int4 index (beg is 8-aligned)
    int4 e0 = epk4[b2 + 0];
    int4 e1 = epk4[b2 + 1];
    int4 e2 = epk4[b2 + 2];
    int4 e3 = epk4[b2 + 3];
    uint4 h0 = H[(size_t)(unsigned)e0.x * 16 + l];
    uint4 h1 = H[(size_t)(unsigned)e0.z * 16 + l];
    uint4 h2 = H[(size_t)(unsigned)e1.x * 16 + l];
    uint4 h3 = H[(size_t)(unsigned)e1.z * 16 + l];
    uint4 h4 = H[(size_t)(unsigned)e2.x * 16 + l];
    uint4 h5 = H[(size_t)(unsigned)e2.z * 16 + l];
    uint4 h6 = H[(size_t)(unsigned)e3.x * 16 + l];
    uint4 h7 = H[(size_t)(unsigned)e3.z * 16 + l];
    fma8(__int_as_float(e0.y), h0, a);
    fma8(__int_as_float(e0.w), h1, a);
    fma8(__int_as_float(e1.y), h2, a);
    fma8(__int_as_float(e1.w), h3, a);
    fma8(__int_as_float(e2.y), h4, a);
    fma8(__int_as_float(e2.w), h5, a);
    fma8(__int_as_float(e3.y), h6, a);
    fma8(__int_as_float(e3.w), h7, a);
  }

  float4 bl = ((const float4*)bias)[l * 2];
  float4 bh = ((const float4*)bias)[l * 2 + 1];
  a[0] = fmaxf(a[0] + bl.x, 0.f); a[1] = fmaxf(a[1] + bl.y, 0.f);
  a[2] = fmaxf(a[2] + bl.z, 0.f); a[3] = fmaxf(a[3] + bl.w, 0.f);
  a[4] = fmaxf(a[4] + bh.x, 0.f); a[5] = fmaxf(a[5] + bh.y, 0.f);
  a[6] = fmaxf(a[6] + bh.z, 0.f); a[7] = fmaxf(a[7] + bh.w, 0.f);
  if (resid) {
    uint4 r = resid[(size_t)node * 16 + l];
    a[0] += bf_lo(r.x); a[1] += bf_hi(r.x);
    a[2] += bf_lo(r.y); a[3] += bf_hi(r.y);
    a[4] += bf_lo(r.z); a[5] += bf_hi(r.z);
    a[6] += bf_lo(r.w); a[7] += bf_hi(r.w);
  }
  if (outb) {
    uint4 o;
    o.x = pack2(a[0], a[1]); o.y = pack2(a[2], a[3]);
    o.z = pack2(a[4], a[5]); o.w = pack2(a[6], a[7]);
    outb[(size_t)node * 16 + l] = o;
  } else {
    float4 o0; o0.x = a[0]; o0.y = a[1]; o0.z = a[2]; o0.w = a[3];
    float4 o1; o1.x = a[4]; o1.y = a[5]; o1.z = a[6]; o1.w = a[7];
    outf[(size_t)node * 32 + l * 2] = o0;
    outf[(size_t)node * 32 + l * 2 + 1] = o1;
  }
}

extern "C" void kernel_launch(void* const* d_in, const int* in_sizes, int n_in,
                              void* d_out, int out_size, void* d_ws, size_t ws_size,
                              hipStream_t stream) {
  const float* x  = (const float*)d_in[0];
  const int* edges = (const int*)d_in[1];
  const float* W0 = (const float*)d_in[2];
  const float* b0 = (const float*)d_in[3];
  const float* W1 = (const float*)d_in[4];
  const float* b1 = (const float*)d_in[5];
  const float* W2 = (const float*)d_in[6];
  const float* b2 = (const float*)d_in[7];
  const float* Wr = (const float*)d_in[8];
  const float* br = (const float*)d_in[9];

  int N = in_sizes[0] / 128;
  int E = in_sizes[1] / 2;
  const int* src = edges;
  const int* dst = edges + E;

  char* ws = (char*)d_ws;
  size_t off = 0;
  auto alloc = [&](size_t bytes) -> void* {
    void* p = ws + off; off = WS_ALIGN(off + bytes); return p;
  };
  int*   cnt    = (int*)  alloc((size_t)N * 4);
  float* dinv   = (float*)alloc((size_t)N * 4);
  int*   rs     = (int*)  alloc((size_t)(N + 1) * 4);
  int*   bsum   = (int*)  alloc(1024);
  int2*  epk    = (int2*) alloc(((size_t)E + 8 * (size_t)N) * 8);  // 8-padded CSR
  unsigned short* xb = (unsigned short*)alloc((size_t)N * 128 * 2);
  unsigned short* Wt = (unsigned short*)alloc((size_t)4 * 16384 * 2);
  unsigned short* A  = (unsigned short*)alloc((size_t)N * 128 * 2);
  unsigned short* Hb = (unsigned short*)alloc((size_t)N * 128 * 2);
  unsigned short* R  = (unsigned short*)alloc((size_t)N * 128 * 2);
  int* pos = (int*)A;   // pos[E] only lives between k_count and k_fill;
                        // A is first written after k_fill completes.
  (void)ws_size; (void)n_in; (void)out_size;

  int nb1 = (N + 1023) / 1024;   // 98 for N=100000 (must be <= 128)

  // ---- fused prep + CSR build ----
  int n4 = N * 128 / 4;
  int zb = (N + 255) / 256;
  int xbn = (n4 + 255) / 256;
  k_prep <<<zb + xbn + 256, 256, 0, stream>>>(x, (unsigned*)xb, n4, cnt, N,
                                              W0, W1, W2, Wr, Wt, zb, xbn);
  k_count<<<(E + 255) / 256, 256, 0, stream>>>(dst, E, cnt, pos);
  k_scan1<<<nb1, 1024, 0, stream>>>(cnt, N, rs, bsum, dinv);
  k_scan2<<<1, 128, 0, stream>>>(bsum, nb1);
  k_fill <<<(E + N + 255) / 256, 256, 0, stream>>>(src, dst, E, rs, bsum, pos,
                                                   cnt, dinv, epk, N);

  // ---- GCN layers ----
  int gb = (N + 63) / 64;
  int ab = (N + 15) / 16;   // 16 nodes (quarter-waves) per 256-thread block

  unsigned short* Wt0 = Wt;
  unsigned short* Wt1 = Wt + 16384;
  unsigned short* Wt2 = Wt + 2 * 16384;
  unsigned short* Wtr = Wt + 3 * 16384;

  k_gemm_mfma<<<gb, 256, 0, stream>>>(xb, Wtr, br, R, N);       // residual
  k_gemm_mfma<<<gb, 256, 0, stream>>>(xb, Wt0, nullptr, A, N);
  k_agg<<<ab, 256, 0, stream>>>((const uint4*)A, rs, bsum, cnt, epk, dinv, b0,
                                (const uint4*)R, (uint4*)Hb, nullptr, N);
  k_gemm_mfma<<<gb, 256, 0, stream>>>(Hb, Wt1, nullptr, A, N);
  k_agg<<<ab, 256, 0, stream>>>((const uint4*)A, rs, bsum, cnt, epk, dinv, b1,
                                nullptr, (uint4*)R, nullptr, N);
  k_gemm_mfma<<<gb, 256, 0, stream>>>(R, Wt2, nullptr, A, N);
  k_agg<<<ab, 256, 0, stream>>>((const uint4*)A, rs, bsum, cnt, epk, dinv, b2,
                                nullptr, nullptr, (float4*)d_out, N);
}